// Round 3
// baseline (2928.613 us; speedup 1.0000x reference)
//
#include <hip/hip_runtime.h>
#include <hip/hip_bf16.h>
#include <stdint.h>

// FATAttention: B=16, T=512, D=256, H=8, E=32, BASIS=8, 20 sinkhorn iters.
// R3: inputs/outputs are FP32 (per reference dtypes). Internal buffers bf16.
// All kernels <=64KB static LDS; M chunked over hb by ws_size.

#define B_  16
#define T_  512
#define D_  256
#define H_  8
#define E_  32
#define HE_ 256
#define KB_ 8
#define HB_ 128

typedef unsigned short u16;
typedef __attribute__((ext_vector_type(8))) short short8;
typedef __attribute__((ext_vector_type(4))) float floatx4;

__device__ __forceinline__ float bflo(uint32_t u){ return __uint_as_float(u << 16); }
__device__ __forceinline__ float bfhi(uint32_t u){ return __uint_as_float(u & 0xffff0000u); }
__device__ __forceinline__ u16 f2bf(float f){ // RTNE
  uint32_t u = __float_as_uint(f);
  return (u16)((u + 0x7fffu + ((u >> 16) & 1u)) >> 16);
}
__device__ __forceinline__ short8 cvt8(const float* p){
  float4 a = *(const float4*)p;
  float4 b = *(const float4*)(p + 4);
  short8 r;
  r[0] = (short)f2bf(a.x); r[1] = (short)f2bf(a.y);
  r[2] = (short)f2bf(a.z); r[3] = (short)f2bf(a.w);
  r[4] = (short)f2bf(b.x); r[5] = (short)f2bf(b.y);
  r[6] = (short)f2bf(b.z); r[7] = (short)f2bf(b.w);
  return r;
}

// ---------------------------------------------------------------- K0: meta
// q_w[t,k] = <te[t,:], Wq_meta[t,k,:]>  (q side pre-scaled by 1/sqrt(E))
__global__ void k0_meta(const float* __restrict__ te, const float* __restrict__ wq,
                        const float* __restrict__ wk, float* __restrict__ qw,
                        float* __restrict__ kw){
  int t = blockIdx.x;
  int lane = threadIdx.x;        // 64
  int k = lane >> 3, part = lane & 7;
  const float* ta = te + t*D_ + part*32;
  const float* qa = wq + (t*KB_ + k)*D_ + part*32;
  const float* ka = wk + (t*KB_ + k)*D_ + part*32;
  float sq = 0.f, sk = 0.f;
  #pragma unroll
  for (int i = 0; i < 8; ++i){
    float4 a = ((const float4*)ta)[i];
    float4 b = ((const float4*)qa)[i];
    float4 c = ((const float4*)ka)[i];
    sq += a.x*b.x + a.y*b.y + a.z*b.z + a.w*b.w;
    sk += a.x*c.x + a.y*c.y + a.z*c.z + a.w*c.w;
  }
  sq += __shfl_down(sq, 4, 8); sq += __shfl_down(sq, 2, 8); sq += __shfl_down(sq, 1, 8);
  sk += __shfl_down(sk, 4, 8); sk += __shfl_down(sk, 2, 8); sk += __shfl_down(sk, 1, 8);
  if (part == 0){
    qw[t*KB_ + k] = sq * 0.17677669529663687f;  // fold 1/sqrt(32) into q path
    kw[t*KB_ + k] = sk;
  }
}

// -------------------------------------------------------------- Kpre
// Asym = 0.5*(A + A^T) fp32; lam = sigmoid(lambda_logits) fp32
__global__ void __launch_bounds__(256)
k_pre(const float* __restrict__ A, const float* __restrict__ L,
      float* __restrict__ Asym, float* __restrict__ lam){
  __shared__ float tile[64][65];
  int I = blockIdx.x >> 3, J = blockIdx.x & 7;
  int tid = threadIdx.x;
  #pragma unroll
  for (int i = 0; i < 16; ++i){
    int idx = tid + 256*i;
    int rr = idx >> 6, cc = idx & 63;
    tile[rr][cc] = A[(J*64 + rr)*T_ + I*64 + cc];
  }
  __syncthreads();
  #pragma unroll
  for (int i = 0; i < 16; ++i){
    int idx = tid + 256*i;
    int rr = idx >> 6, cc = idx & 63;
    int t = I*64 + rr, s = J*64 + cc;
    Asym[t*T_ + s] = 0.5f*(A[t*T_ + s] + tile[cc][rr]);
    lam[t*T_ + s] = 1.0f / (1.0f + __expf(-L[t*T_ + s]));
  }
}

// ---------------------------------------------------------------- K1: q/k/v
// Per token t: mix Q~/K~ (or copy W_V) transposed [e][d] into 64KB LDS
// (two e-halves of 128), then [16,256]@[256,128] bf16 MFMA per half.
// LDS layout XOR-swizzled: elem (el,d) at el*256 + (((d>>3) ^ (el&31))<<3) + (d&7).
__global__ void __launch_bounds__(512)
k1_qkv(const float* __restrict__ X, const float* __restrict__ Qb, const float* __restrict__ Kb,
       const float* __restrict__ WV, const float* __restrict__ qw, const float* __restrict__ kw,
       u16* __restrict__ q_ws, u16* __restrict__ k_ws, u16* __restrict__ v_ws){
  __shared__ u16 lds[128*256];   // 65536 B
  int t = blockIdx.x;
  int tid = threadIdx.x;
  float wq8[8], wk8[8];
  #pragma unroll
  for (int k = 0; k < 8; ++k){ wq8[k] = qw[t*8 + k]; wk8[k] = kw[t*8 + k]; }

  int d = tid >> 1;              // 0..255
  int esub = (tid & 1) * 64;     // 0 / 64 (within 128-half)
  int lane = tid & 63, wv = tid >> 6;
  int q_l = lane >> 4, c_l = lane & 15;

  // A-fragments: X[b=c_l, t, :] converted to bf16 once, reused for all 6 GEMMs
  short8 afrag[8];
  #pragma unroll
  for (int kk = 0; kk < 8; ++kk)
    afrag[kk] = cvt8(&X[((size_t)c_l*T_ + t)*D_ + kk*32 + q_l*8]);

  for (int phase = 0; phase < 3; ++phase){
    u16* dst = (phase == 0) ? q_ws : (phase == 1) ? k_ws : v_ws;
    for (int eh = 0; eh < 2; ++eh){
      // ---- stage this half's weights transposed+swizzled into LDS ----
      #pragma unroll 1
      for (int i = 0; i < 8; ++i){
        int el0 = esub + 8*i;
        int eg0 = eh*128 + el0;
        float v[8];
        if (phase == 2){
          const float* p = &WV[((size_t)t*D_ + d)*HE_ + eg0];
          float4 m0 = *(const float4*)p;
          float4 m1 = *(const float4*)(p + 4);
          v[0]=m0.x; v[1]=m0.y; v[2]=m0.z; v[3]=m0.w;
          v[4]=m1.x; v[5]=m1.y; v[6]=m1.z; v[7]=m1.w;
        } else {
          const float* base = (phase == 0) ? Qb : Kb;
          const float* w8 = (phase == 0) ? wq8 : wk8;
          #pragma unroll
          for (int j = 0; j < 8; ++j) v[j] = 0.f;
          #pragma unroll
          for (int k = 0; k < 8; ++k){
            const float* p = &base[((size_t)k*D_ + d)*HE_ + eg0];
            float4 m0 = *(const float4*)p;
            float4 m1 = *(const float4*)(p + 4);
            float wkk = w8[k];
            v[0] += wkk*m0.x; v[1] += wkk*m0.y; v[2] += wkk*m0.z; v[3] += wkk*m0.w;
            v[4] += wkk*m1.x; v[5] += wkk*m1.y; v[6] += wkk*m1.z; v[7] += wkk*m1.w;
          }
        }
        #pragma unroll
        for (int j = 0; j < 8; ++j){
          int el = el0 + j;
          lds[el*256 + (((d>>3) ^ (el&31))<<3) + (d&7)] = f2bf(v[j]);
        }
      }
      __syncthreads();
      // ---- GEMM: A = X[:,t,:] [16,256]; wave wv owns e-tile el=wv*16..+15 ----
      floatx4 acc = {0,0,0,0};
      int el = wv*16 + c_l;
      #pragma unroll
      for (int kk = 0; kk < 8; ++kk){
        int c = kk*4 + q_l;
        short8 bf = *(const short8*)&lds[el*256 + ((c ^ (el&31))<<3)];
        acc = __builtin_amdgcn_mfma_f32_16x16x32_bf16(afrag[kk], bf, acc, 0, 0, 0);
      }
      int e_full = eh*128 + wv*16 + c_l;
      #pragma unroll
      for (int r = 0; r < 4; ++r){
        int b = q_l*4 + r;
        dst[(((size_t)(e_full >> 5)*B_ + b)*T_ + t)*E_ + (e_full & 31)] = f2bf(acc[r]);
      }
      __syncthreads();
    }
  }
}

// ---------------------------------------------------------------- K2a: att
// scores (q pre-scaled) -> row softmax -> lam*Asym + (1-lam)*p -> Mc (mixed att)
__global__ void __launch_bounds__(256)
k2a_att(const u16* __restrict__ q_ws, const u16* __restrict__ k_ws,
        const float* __restrict__ Asym, const float* __restrict__ lam,
        u16* __restrict__ Mc, int hb0){
  int tt = blockIdx.x;       // 0..7  (t-tile of 64)
  int hbl = blockIdx.y;
  int hb = hb0 + hbl;
  int tid = threadIdx.x;
  int lane = tid & 63, wv = tid >> 6;
  int q_l = lane >> 4, c_l = lane & 15;
  int t0 = tt*64 + wv*16;
  const u16* qb = q_ws + (size_t)hb*T_*E_;
  const u16* kb = k_ws + (size_t)hb*T_*E_;
  short8 af = *(const short8*)&qb[(t0 + c_l)*E_ + q_l*8];
  floatx4 acc[32];
  #pragma unroll
  for (int st = 0; st < 32; ++st){
    short8 bf = *(const short8*)&kb[(st*16 + c_l)*E_ + q_l*8];
    floatx4 z = {0,0,0,0};
    acc[st] = __builtin_amdgcn_mfma_f32_16x16x32_bf16(af, bf, z, 0, 0, 0);
  }
  #pragma unroll
  for (int r = 0; r < 4; ++r){
    float mx = -1e30f;
    #pragma unroll
    for (int st = 0; st < 32; ++st) mx = fmaxf(mx, acc[st][r]);
    mx = fmaxf(mx, __shfl_xor(mx, 1)); mx = fmaxf(mx, __shfl_xor(mx, 2));
    mx = fmaxf(mx, __shfl_xor(mx, 4)); mx = fmaxf(mx, __shfl_xor(mx, 8));
    float sum = 0.f;
    #pragma unroll
    for (int st = 0; st < 32; ++st){ float e = __expf(acc[st][r] - mx); acc[st][r] = e; sum += e; }
    sum += __shfl_xor(sum, 1); sum += __shfl_xor(sum, 2);
    sum += __shfl_xor(sum, 4); sum += __shfl_xor(sum, 8);
    float inv = 1.0f / sum;
    #pragma unroll
    for (int st = 0; st < 32; ++st) acc[st][r] *= inv;
  }
  size_t ob = (size_t)hbl*T_*T_;
  #pragma unroll 1
  for (int st = 0; st < 32; ++st){
    #pragma unroll
    for (int r = 0; r < 4; ++r){
      int t = t0 + q_l*4 + r;
      int s = st*16 + c_l;
      float lv = lam[t*T_ + s];
      float av = Asym[t*T_ + s];
      Mc[ob + (size_t)t*T_ + s] = f2bf(lv*av + (1.f - lv)*acc[st][r]);
    }
  }
}

// ---------------------------------------------------------------- K2b: M
// In-place on Mc: M = exp(0.5*(att + att^T)), via triangular 64x64 tile pairs.
__global__ void __launch_bounds__(256)
k2b_sym(u16* __restrict__ Mc){
  __shared__ u16 tA[64][65], tB[64][65];
  int p = blockIdx.x, I = 0;           // p in [0,36): (I,J) with I<=J
  while (p >= 8 - I){ p -= 8 - I; ++I; }
  int J = I + p;
  int hbl = blockIdx.y;
  size_t base = (size_t)hbl*T_*T_;
  int tid = threadIdx.x;
  #pragma unroll
  for (int i = 0; i < 16; ++i){
    int idx = tid + 256*i;
    int rr = idx >> 6, cc = idx & 63;
    tA[rr][cc] = Mc[base + (size_t)(I*64 + rr)*T_ + J*64 + cc];
    tB[rr][cc] = Mc[base + (size_t)(J*64 + rr)*T_ + I*64 + cc];
  }
  __syncthreads();
  #pragma unroll
  for (int i = 0; i < 16; ++i){
    int idx = tid + 256*i;
    int rr = idx >> 6, cc = idx & 63;
    float a = bflo((uint32_t)tA[rr][cc]);
    float b = bflo((uint32_t)tB[cc][rr]);
    Mc[base + (size_t)(I*64 + rr)*T_ + J*64 + cc] = f2bf(__expf(0.5f*(a + b)));
  }
  if (I != J){
    #pragma unroll
    for (int i = 0; i < 16; ++i){
      int idx = tid + 256*i;
      int rr = idx >> 6, cc = idx & 63;
      float a = bflo((uint32_t)tB[rr][cc]);
      float b = bflo((uint32_t)tA[cc][rr]);
      Mc[base + (size_t)(J*64 + rr)*T_ + I*64 + cc] = f2bf(__expf(0.5f*(a + b)));
    }
  }
}

// ---------------------------------------------------------------- K3: sinkhorn
// Normal-space symmetric Sinkhorn: r = 1/(M c); c = 1/(M r). M row resident:
// cols 0..455 in 228 VGPR dwords, cols 456..511 in LDS [colpair][t]. 61KB LDS.
#define K3_RC 228
#define K3_LC 28
__global__ void __launch_bounds__(512)
k3_sinkhorn(const u16* __restrict__ Mc, float* __restrict__ r_ws, float* __restrict__ c_ws,
            int hb0){
  __shared__ uint32_t mlds[K3_LC*512];   // 57344 B
  __shared__ float buf0[512], buf1[512]; // 4096 B
  int hbl = blockIdx.x;
  int t = threadIdx.x;
  const uint4* row = (const uint4*)(Mc + (size_t)(hbl*T_ + t)*T_);
  uint32_t mreg[K3_RC];
  #pragma unroll
  for (int i = 0; i < 57; ++i){
    uint4 v = row[i];
    mreg[4*i] = v.x; mreg[4*i+1] = v.y; mreg[4*i+2] = v.z; mreg[4*i+3] = v.w;
  }
  #pragma unroll
  for (int i = 0; i < 7; ++i){
    uint4 v = row[57 + i];
    mlds[(4*i + 0)*512 + t] = v.x;
    mlds[(4*i + 1)*512 + t] = v.y;
    mlds[(4*i + 2)*512 + t] = v.z;
    mlds[(4*i + 3)*512 + t] = v.w;
  }
  buf0[t] = 1.0f;
  __syncthreads();
  float lastr = 0.f, lastc = 1.0f;
  #pragma unroll 1
  for (int p = 0; p < 40; ++p){
    const float* rd = (p & 1) ? buf1 : buf0;
    float* wr = (p & 1) ? buf0 : buf1;
    float a0 = 0.f, a1 = 0.f, a2 = 0.f, a3 = 0.f;   // 4-way split accumulators
    #pragma unroll
    for (int i = 0; i < K3_RC; i += 2){
      float4 w = *(const float4*)&rd[2*i];          // wave-uniform broadcast
      uint32_t m0 = mreg[i], m1 = mreg[i+1];
      a0 += bflo(m0)*w.x; a1 += bfhi(m0)*w.y;
      a2 += bflo(m1)*w.z; a3 += bfhi(m1)*w.w;
    }
    #pragma unroll
    for (int cp = 0; cp < K3_LC; cp += 2){
      float4 w = *(const float4*)&rd[456 + 2*cp];   // broadcast
      uint32_t m0 = mlds[cp*512 + t];
      uint32_t m1 = mlds[(cp + 1)*512 + t];
      a0 += bflo(m0)*w.x; a1 += bfhi(m0)*w.y;
      a2 += bflo(m1)*w.z; a3 += bfhi(m1)*w.w;
    }
    float nv = 1.0f / ((a0 + a1) + (a2 + a3));
    wr[t] = nv;
    if (p & 1) lastc = nv; else lastr = nv;
    __syncthreads();
  }
  int hb = hb0 + hbl;
  r_ws[hb*T_ + t] = lastr;
  c_ws[hb*T_ + t] = lastc;
}

// ---------------------------------------------------------------- K4: out
// out[b,t,h*32+e] = r[t] * sum_s M[t,s] * (c[s]*V[s,e])   (fp32 out)
#define K4_VS 520
__global__ void __launch_bounds__(256)
k4_out(const u16* __restrict__ Mc, const u16* __restrict__ v_ws,
       const float* __restrict__ r_ws, const float* __restrict__ c_ws,
       float* __restrict__ out, int hb0){
  __shared__ u16 vt[32*K4_VS + 8];   // 33296 B
  int th = blockIdx.x;       // t-half
  int hbl = blockIdx.y;
  int hb = hb0 + hbl;
  int h = hb >> 4, b = hb & 15;
  int tid = threadIdx.x;
  const u16* vb = v_ws + (size_t)hb*T_*E_;
  const float* cvec = c_ws + hb*T_;
  #pragma unroll
  for (int rr = 0; rr < 2; ++rr){
    int s = tid + rr*256;
    float cs = cvec[s];
    #pragma unroll
    for (int j4 = 0; j4 < 4; ++j4){
      uint4 v = *(const uint4*)&vb[s*E_ + j4*8];
      uint32_t vv[4] = {v.x,v.y,v.z,v.w};
      #pragma unroll
      for (int j = 0; j < 4; ++j){
        vt[(j4*8 + 2*j    )*K4_VS + s] = f2bf(bflo(vv[j])*cs);
        vt[(j4*8 + 2*j + 1)*K4_VS + s] = f2bf(bfhi(vv[j])*cs);
      }
    }
  }
  __syncthreads();
  int lane = tid & 63, wv = tid >> 6;
  int q_l = lane >> 4, c_l = lane & 15;
  const float* rvec = r_ws + hb*T_;
  const u16* mrow = Mc + (size_t)hbl*T_*T_;
  #pragma unroll 1
  for (int mt = 0; mt < 4; ++mt){
    int t0 = th*256 + (wv*4 + mt)*16;
    floatx4 acc0 = {0,0,0,0}, acc1 = {0,0,0,0};
    #pragma unroll
    for (int kk = 0; kk < 16; ++kk){
      int k0 = kk*32;
      short8 af = *(const short8*)&mrow[(size_t)(t0 + c_l)*T_ + k0 + q_l*8];
      short8 b0 = *(const short8*)&vt[(0  + c_l)*K4_VS + k0 + q_l*8];
      short8 b1 = *(const short8*)&vt[(16 + c_l)*K4_VS + k0 + q_l*8];
      acc0 = __builtin_amdgcn_mfma_f32_16x16x32_bf16(af, b0, acc0, 0, 0, 0);
      acc1 = __builtin_amdgcn_mfma_f32_16x16x32_bf16(af, b1, acc1, 0, 0, 0);
    }
    #pragma unroll
    for (int r = 0; r < 4; ++r){
      int t = t0 + q_l*4 + r;
      float rt = rvec[t];
      out[((size_t)(b*T_ + t))*HE_ + h*E_ + 0  + c_l] = acc0[r]*rt;
      out[((size_t)(b*T_ + t))*HE_ + h*E_ + 16 + c_l] = acc1[r]*rt;
    }
  }
}

// ---------------------------------------------------------------- launch
extern "C" void kernel_launch(void* const* d_in, const int* in_sizes, int n_in,
                              void* d_out, int out_size, void* d_ws, size_t ws_size,
                              hipStream_t stream){
  const float* X  = (const float*)d_in[0];
  const float* te = (const float*)d_in[1];
  const float* Wq = (const float*)d_in[2];
  const float* Wk = (const float*)d_in[3];
  const float* Qb = (const float*)d_in[4];
  const float* Kb = (const float*)d_in[5];
  const float* WV = (const float*)d_in[6];
  const float* Al = (const float*)d_in[7];
  const float* Ll = (const float*)d_in[8];
  float* out = (float*)d_out;
  (void)in_sizes; (void)n_in; (void)out_size;

  char* w = (char*)d_ws;
  float* qw   = (float*)w;  w += 16384;
  float* kw   = (float*)w;  w += 16384;
  float* Asym = (float*)w;  w += 1048576;
  float* lam  = (float*)w;  w += 1048576;
  u16* q_ws   = (u16*)w;    w += 4194304;
  u16* k_ws   = (u16*)w;    w += 4194304;
  u16* v_ws   = (u16*)w;    w += 4194304;
  float* r_ws = (float*)w;  w += 262144;
  float* c_ws = (float*)w;  w += 262144;
  u16* Mc     = (u16*)w;    // nhb * 512KB
  size_t fixed = (size_t)(w - (char*)d_ws);

  // hb-chunk: largest power of two whose M slab fits in the workspace.
  int nhb = HB_;
  while (nhb > 1 && fixed + (size_t)nhb*T_*T_*2 > ws_size) nhb >>= 1;

  k0_meta<<<T_, 64, 0, stream>>>(te, Wq, Wk, qw, kw);
  k_pre<<<64, 256, 0, stream>>>(Al, Ll, Asym, lam);
  k1_qkv<<<T_, 512, 0, stream>>>(X, Qb, Kb, WV, qw, kw, q_ws, k_ws, v_ws);
  for (int hb0 = 0; hb0 < HB_; hb0 += nhb){
    k2a_att<<<dim3(8, nhb), 256, 0, stream>>>(q_ws, k_ws, Asym, lam, Mc, hb0);
    k2b_sym<<<dim3(36, nhb), 256, 0, stream>>>(Mc);
    k3_sinkhorn<<<nhb, 512, 0, stream>>>(Mc, r_ws, c_ws, hb0);
    k4_out<<<dim3(2, nhb), 256, 0, stream>>>(Mc, v_ws, r_ws, c_ws, out, hb0);
  }
}

// Round 4
// 2570.990 us; speedup vs baseline: 1.1391x; 1.1391x over previous
//
#include <hip/hip_runtime.h>
#include <hip/hip_bf16.h>
#include <stdint.h>

// FATAttention: B=16, T=512, D=256, H=8, E=32, BASIS=8, 20 sinkhorn iters.
// R4: (1) k3 spill fix: __launch_bounds__(512,2) -> 256 VGPRs, 226 reg-dwords
//     + 30 LDS-dwords per row. (2) basis-first QKV: transpose bases to bf16,
//     16 MFMA GEMMs -> Y, mix with per-token weights. (3) bf16 lam/Asym packs.

#define B_  16
#define T_  512
#define D_  256
#define H_  8
#define E_  32
#define HE_ 256
#define KB_ 8
#define HB_ 128

typedef unsigned short u16;
typedef __attribute__((ext_vector_type(8))) short short8;
typedef __attribute__((ext_vector_type(4))) float floatx4;

__device__ __forceinline__ float bflo(uint32_t u){ return __uint_as_float(u << 16); }
__device__ __forceinline__ float bfhi(uint32_t u){ return __uint_as_float(u & 0xffff0000u); }
__device__ __forceinline__ u16 f2bf(float f){ // RTNE
  uint32_t u = __float_as_uint(f);
  return (u16)((u + 0x7fffu + ((u >> 16) & 1u)) >> 16);
}
__device__ __forceinline__ uint32_t pk2(float a, float b){
  return (uint32_t)f2bf(a) | ((uint32_t)f2bf(b) << 16);
}

// ---------------------------------------------------------------- Kcvt: X->bf16
__global__ void __launch_bounds__(256)
kcvt_x(const float* __restrict__ X, u16* __restrict__ Xb){
  int idx = (blockIdx.x*256 + threadIdx.x)*4;
  float4 v = *(const float4*)(X + idx);
  uint2 o; o.x = pk2(v.x, v.y); o.y = pk2(v.z, v.w);
  *(uint2*)(Xb + idx) = o;
}

// ---------------------------------------------------------------- KT: basis^T
// Q_basis/K_basis [k][d][e] fp32 -> QbT/KbT [k][e][d] bf16
__global__ void __launch_bounds__(256)
kT_basis(const float* __restrict__ Qb, const float* __restrict__ Kb,
         u16* __restrict__ QbT, u16* __restrict__ KbT){
  __shared__ float tile[64][65];
  int slot = blockIdx.y;     // 0..15
  const float* src = (slot < 8) ? Qb + (size_t)slot*D_*HE_ : Kb + (size_t)(slot-8)*D_*HE_;
  u16*         dst = (slot < 8) ? QbT + (size_t)slot*HE_*D_ : KbT + (size_t)(slot-8)*HE_*D_;
  int ti = blockIdx.x >> 2, tj = blockIdx.x & 3;   // d-tile, e-tile
  int tid = threadIdx.x;
  #pragma unroll
  for (int i = 0; i < 16; ++i){
    int idx = tid + 256*i;
    int rr = idx >> 6, cc = idx & 63;
    tile[rr][cc] = src[(size_t)(ti*64 + rr)*HE_ + tj*64 + cc];
  }
  __syncthreads();
  #pragma unroll
  for (int i = 0; i < 16; ++i){
    int idx = tid + 256*i;
    int rr = idx >> 6, cc = idx & 63;
    dst[(size_t)(tj*64 + rr)*D_ + ti*64 + cc] = f2bf(tile[cc][rr]);
  }
}

// ---------------------------------------------------------------- K0: meta
__global__ void k0_meta(const float* __restrict__ te, const float* __restrict__ wq,
                        const float* __restrict__ wk, float* __restrict__ qw,
                        float* __restrict__ kw){
  int t = blockIdx.x;
  int lane = threadIdx.x;        // 64
  int k = lane >> 3, part = lane & 7;
  const float* ta = te + t*D_ + part*32;
  const float* qa = wq + (t*KB_ + k)*D_ + part*32;
  const float* ka = wk + (t*KB_ + k)*D_ + part*32;
  float sq = 0.f, sk = 0.f;
  #pragma unroll
  for (int i = 0; i < 8; ++i){
    float4 a = ((const float4*)ta)[i];
    float4 b = ((const float4*)qa)[i];
    float4 c = ((const float4*)ka)[i];
    sq += a.x*b.x + a.y*b.y + a.z*b.z + a.w*b.w;
    sk += a.x*c.x + a.y*c.y + a.z*c.z + a.w*c.w;
  }
  sq += __shfl_down(sq, 4, 8); sq += __shfl_down(sq, 2, 8); sq += __shfl_down(sq, 1, 8);
  sk += __shfl_down(sk, 4, 8); sk += __shfl_down(sk, 2, 8); sk += __shfl_down(sk, 1, 8);
  if (part == 0){
    qw[t*KB_ + k] = sq * 0.17677669529663687f;  // fold 1/sqrt(32) into q path
    kw[t*KB_ + k] = sk;
  }
}

// -------------------------------------------------------------- Kpre
// lA = sigmoid(L)*0.5*(A+A^T) bf16;  oml = 1-sigmoid(L) bf16
__global__ void __launch_bounds__(256)
k_pre(const float* __restrict__ A, const float* __restrict__ L,
      u16* __restrict__ lA, u16* __restrict__ oml){
  __shared__ float tile[64][65];
  int I = blockIdx.x >> 3, J = blockIdx.x & 7;
  int tid = threadIdx.x;
  #pragma unroll
  for (int i = 0; i < 16; ++i){
    int idx = tid + 256*i;
    int rr = idx >> 6, cc = idx & 63;
    tile[rr][cc] = A[(J*64 + rr)*T_ + I*64 + cc];
  }
  __syncthreads();
  #pragma unroll
  for (int i = 0; i < 16; ++i){
    int idx = tid + 256*i;
    int rr = idx >> 6, cc = idx & 63;
    int t = I*64 + rr, s = J*64 + cc;
    float lamv = 1.0f / (1.0f + __expf(-L[t*T_ + s]));
    float asym = 0.5f*(A[t*T_ + s] + tile[cc][rr]);
    lA[t*T_ + s]  = f2bf(lamv*asym);
    oml[t*T_ + s] = f2bf(1.0f - lamv);
  }
}

// ---------------------------------------------------------------- K1a: Y GEMMs
// Y[kb][bt][e] = Xb[bt][:] . basis[kb][:][e]   (8 GEMMs [8192,256]@[256,256])
// LDS tiles 128x32 bf16, pad 40 (2-way banks = free). grid (64, 2, 8).
__global__ void __launch_bounds__(256)
k1a_gemm(const u16* __restrict__ Xb, const u16* __restrict__ BT, u16* __restrict__ Y){
  __shared__ u16 At[128*40];
  __shared__ u16 Bt[128*40];
  int bt0 = blockIdx.x*128;
  int j   = blockIdx.y;        // e-half
  int kb  = blockIdx.z;
  const u16* Bsrc = BT + (size_t)kb*HE_*D_;
  int tid = threadIdx.x, lane = tid & 63, w = tid >> 6;
  int q_l = lane >> 4, c_l = lane & 15;
  int srow = tid >> 2, sch = (tid & 3)*8;
  floatx4 acc[2][8];
  #pragma unroll
  for (int mt = 0; mt < 2; ++mt)
    #pragma unroll
    for (int n = 0; n < 8; ++n) acc[mt][n] = (floatx4){0,0,0,0};

  #pragma unroll 1
  for (int ks = 0; ks < 8; ++ks){
    int k0 = ks*32;
    if (ks) __syncthreads();
    *(short8*)&At[srow*40 + sch] = *(const short8*)&Xb[(size_t)(bt0 + srow)*D_ + k0 + sch];
    *(short8*)&Bt[srow*40 + sch] = *(const short8*)&Bsrc[(size_t)(j*128 + srow)*D_ + k0 + sch];
    __syncthreads();
    short8 a0 = *(const short8*)&At[(w*32 +  0 + c_l)*40 + q_l*8];
    short8 a1 = *(const short8*)&At[(w*32 + 16 + c_l)*40 + q_l*8];
    #pragma unroll
    for (int n = 0; n < 8; ++n){
      short8 bfr = *(const short8*)&Bt[(n*16 + c_l)*40 + q_l*8];
      acc[0][n] = __builtin_amdgcn_mfma_f32_16x16x32_bf16(a0, bfr, acc[0][n], 0, 0, 0);
      acc[1][n] = __builtin_amdgcn_mfma_f32_16x16x32_bf16(a1, bfr, acc[1][n], 0, 0, 0);
    }
  }
  #pragma unroll
  for (int mt = 0; mt < 2; ++mt)
    #pragma unroll
    for (int n = 0; n < 8; ++n)
      #pragma unroll
      for (int r = 0; r < 4; ++r){
        int row = w*32 + mt*16 + q_l*4 + r;
        int e = j*128 + n*16 + c_l;
        Y[((size_t)kb << 21) + (size_t)(bt0 + row)*HE_ + e] = f2bf(acc[mt][n][r]);
      }
}

// ---------------------------------------------------------------- K1b: mix
// dst[h][b][t][e&31] = sum_k wv[t,k] * Y[k][b*T+t][e]
__global__ void __launch_bounds__(256)
k1b_mix(const u16* __restrict__ Y, const float* __restrict__ wv, u16* __restrict__ dst){
  int tid = threadIdx.x;
  int row = blockIdx.x*16 + (tid >> 4);
  int e0 = (tid & 15)*16;
  int b = row >> 9, t = row & 511;
  float w8[8];
  #pragma unroll
  for (int k = 0; k < 8; ++k) w8[k] = wv[t*8 + k];
  float acc[16];
  #pragma unroll
  for (int i = 0; i < 16; ++i) acc[i] = 0.f;
  #pragma unroll
  for (int k = 0; k < 8; ++k){
    const u16* yp = Y + ((size_t)k << 21) + (size_t)row*HE_ + e0;
    uint4 v0 = *(const uint4*)yp;
    uint4 v1 = *(const uint4*)(yp + 8);
    uint32_t vv[8] = {v0.x,v0.y,v0.z,v0.w,v1.x,v1.y,v1.z,v1.w};
    float wk = w8[k];
    #pragma unroll
    for (int d = 0; d < 8; ++d){
      acc[2*d]   += wk*bflo(vv[d]);
      acc[2*d+1] += wk*bfhi(vv[d]);
    }
  }
  uint4 o0, o1;
  o0.x = pk2(acc[0],acc[1]);   o0.y = pk2(acc[2],acc[3]);
  o0.z = pk2(acc[4],acc[5]);   o0.w = pk2(acc[6],acc[7]);
  o1.x = pk2(acc[8],acc[9]);   o1.y = pk2(acc[10],acc[11]);
  o1.z = pk2(acc[12],acc[13]); o1.w = pk2(acc[14],acc[15]);
  int h = e0 >> 5, off = e0 & 31;
  u16* dp = dst + (((size_t)(h*16 + b)*T_ + t)*E_ + off);
  *(uint4*)dp = o0;
  *(uint4*)(dp + 8) = o1;
}

// ---------------------------------------------------------------- K1c: values
// v_ws[h][b][t][e] = Xb[b,t,:] . W_V[t,:,:]  (per-token GEMM, streams W_V once)
__global__ void __launch_bounds__(512)
k1c_v(const u16* __restrict__ Xb, const float* __restrict__ WV, u16* __restrict__ v_ws){
  __shared__ u16 lds[128*256];   // 65536 B
  int t = blockIdx.x;
  int tid = threadIdx.x;
  int d = tid >> 1, esub = (tid & 1)*64;
  int lane = tid & 63, wv = tid >> 6;
  int q_l = lane >> 4, c_l = lane & 15;
  short8 afrag[8];
  #pragma unroll
  for (int kk = 0; kk < 8; ++kk)
    afrag[kk] = *(const short8*)&Xb[((size_t)c_l*T_ + t)*D_ + kk*32 + q_l*8];
  for (int eh = 0; eh < 2; ++eh){
    #pragma unroll 1
    for (int i = 0; i < 8; ++i){
      int el0 = esub + 8*i;
      int eg0 = eh*128 + el0;
      const float* p = &WV[((size_t)t*D_ + d)*HE_ + eg0];
      float4 m0 = *(const float4*)p;
      float4 m1 = *(const float4*)(p + 4);
      float v[8] = {m0.x,m0.y,m0.z,m0.w,m1.x,m1.y,m1.z,m1.w};
      #pragma unroll
      for (int jj = 0; jj < 8; ++jj){
        int el = el0 + jj;
        lds[el*256 + (((d>>3) ^ (el&31))<<3) + (d&7)] = f2bf(v[jj]);
      }
    }
    __syncthreads();
    floatx4 acc = {0,0,0,0};
    int el = wv*16 + c_l;
    #pragma unroll
    for (int kk = 0; kk < 8; ++kk){
      int c = kk*4 + q_l;
      short8 bfr = *(const short8*)&lds[el*256 + ((c ^ (el&31))<<3)];
      acc = __builtin_amdgcn_mfma_f32_16x16x32_bf16(afrag[kk], bfr, acc, 0, 0, 0);
    }
    int e_full = eh*128 + wv*16 + c_l;
    #pragma unroll
    for (int r = 0; r < 4; ++r){
      int b = q_l*4 + r;
      v_ws[(((size_t)(e_full >> 5)*B_ + b)*T_ + t)*E_ + (e_full & 31)] = f2bf(acc[r]);
    }
    __syncthreads();
  }
}

// ---------------------------------------------------------------- K2a: att
__global__ void __launch_bounds__(256)
k2a_att(const u16* __restrict__ q_ws, const u16* __restrict__ k_ws,
        const u16* __restrict__ lA, const u16* __restrict__ oml,
        u16* __restrict__ Mc, int hb0){
  int tt = blockIdx.x;       // 0..7  (t-tile of 64)
  int hbl = blockIdx.y;
  int hb = hb0 + hbl;
  int tid = threadIdx.x;
  int lane = tid & 63, wv = tid >> 6;
  int q_l = lane >> 4, c_l = lane & 15;
  int t0 = tt*64 + wv*16;
  const u16* qb = q_ws + (size_t)hb*T_*E_;
  const u16* kb = k_ws + (size_t)hb*T_*E_;
  short8 af = *(const short8*)&qb[(t0 + c_l)*E_ + q_l*8];
  floatx4 acc[32];
  #pragma unroll
  for (int st = 0; st < 32; ++st){
    short8 bfr = *(const short8*)&kb[(st*16 + c_l)*E_ + q_l*8];
    floatx4 z = {0,0,0,0};
    acc[st] = __builtin_amdgcn_mfma_f32_16x16x32_bf16(af, bfr, z, 0, 0, 0);
  }
  #pragma unroll
  for (int r = 0; r < 4; ++r){
    float mx = -1e30f;
    #pragma unroll
    for (int st = 0; st < 32; ++st) mx = fmaxf(mx, acc[st][r]);
    mx = fmaxf(mx, __shfl_xor(mx, 1)); mx = fmaxf(mx, __shfl_xor(mx, 2));
    mx = fmaxf(mx, __shfl_xor(mx, 4)); mx = fmaxf(mx, __shfl_xor(mx, 8));
    float sum = 0.f;
    #pragma unroll
    for (int st = 0; st < 32; ++st){ float e = __expf(acc[st][r] - mx); acc[st][r] = e; sum += e; }
    sum += __shfl_xor(sum, 1); sum += __shfl_xor(sum, 2);
    sum += __shfl_xor(sum, 4); sum += __shfl_xor(sum, 8);
    float inv = 1.0f / sum;
    #pragma unroll
    for (int st = 0; st < 32; ++st) acc[st][r] *= inv;
  }
  size_t ob = (size_t)hbl*T_*T_;
  #pragma unroll 1
  for (int st = 0; st < 32; ++st){
    #pragma unroll
    for (int r = 0; r < 4; ++r){
      int t = t0 + q_l*4 + r;
      int s = st*16 + c_l;
      float la = bflo((uint32_t)lA[t*T_ + s]);
      float om = bflo((uint32_t)oml[t*T_ + s]);
      Mc[ob + (size_t)t*T_ + s] = f2bf(la + om*acc[st][r]);
    }
  }
}

// ---------------------------------------------------------------- K2b: M
// In-place: M = exp(0.5*(att + att^T)), triangular 64x64 tile pairs.
__global__ void __launch_bounds__(256)
k2b_sym(u16* __restrict__ Mc){
  __shared__ u16 tA[64][65], tB[64][65];
  int p = blockIdx.x, I = 0;           // p in [0,36): (I,J) with I<=J
  while (p >= 8 - I){ p -= 8 - I; ++I; }
  int J = I + p;
  int hbl = blockIdx.y;
  size_t base = (size_t)hbl*T_*T_;
  int tid = threadIdx.x;
  #pragma unroll
  for (int i = 0; i < 16; ++i){
    int idx = tid + 256*i;
    int rr = idx >> 6, cc = idx & 63;
    tA[rr][cc] = Mc[base + (size_t)(I*64 + rr)*T_ + J*64 + cc];
    tB[rr][cc] = Mc[base + (size_t)(J*64 + rr)*T_ + I*64 + cc];
  }
  __syncthreads();
  #pragma unroll
  for (int i = 0; i < 16; ++i){
    int idx = tid + 256*i;
    int rr = idx >> 6, cc = idx & 63;
    float a = bflo((uint32_t)tA[rr][cc]);
    float b = bflo((uint32_t)tB[cc][rr]);
    Mc[base + (size_t)(I*64 + rr)*T_ + J*64 + cc] = f2bf(__expf(0.5f*(a + b)));
  }
  if (I != J){
    #pragma unroll
    for (int i = 0; i < 16; ++i){
      int idx = tid + 256*i;
      int rr = idx >> 6, cc = idx & 63;
      float a = bflo((uint32_t)tB[rr][cc]);
      float b = bflo((uint32_t)tA[cc][rr]);
      Mc[base + (size_t)(J*64 + rr)*T_ + I*64 + cc] = f2bf(__expf(0.5f*(a + b)));
    }
  }
}

// ---------------------------------------------------------------- K3: sinkhorn
// r = 1/(M c); c = 1/(M r), M symmetric. Row resident: cols 0..451 in 226 VGPR
// dwords, cols 452..511 in 30 LDS dword-columns. 64 KB LDS, 256-VGPR cap.
#define K3_RC 226
#define K3_LC 30
__global__ void __launch_bounds__(512, 2)
k3_sinkhorn(const u16* __restrict__ Mc, float* __restrict__ r_ws, float* __restrict__ c_ws,
            int hb0){
  __shared__ uint32_t mlds[K3_LC*512];   // 61440 B
  __shared__ float buf0[512], buf1[512]; // 4096 B  (total exactly 64 KB)
  int hbl = blockIdx.x;
  int t = threadIdx.x;
  const uint4* row = (const uint4*)(Mc + (size_t)(hbl*T_ + t)*T_);
  uint32_t mreg[K3_RC];
  #pragma unroll
  for (int i = 0; i < 56; ++i){          // dwords 0..223
    uint4 v = row[i];
    mreg[4*i] = v.x; mreg[4*i+1] = v.y; mreg[4*i+2] = v.z; mreg[4*i+3] = v.w;
  }
  {                                       // dwords 224..227
    uint4 v = row[56];
    mreg[224] = v.x; mreg[225] = v.y;
    mlds[0*512 + t] = v.z; mlds[1*512 + t] = v.w;
  }
  #pragma unroll
  for (int i = 0; i < 7; ++i){            // dwords 228..255 -> mlds[2..29]
    uint4 v = row[57 + i];
    mlds[(2 + 4*i + 0)*512 + t] = v.x;
    mlds[(2 + 4*i + 1)*512 + t] = v.y;
    mlds[(2 + 4*i + 2)*512 + t] = v.z;
    mlds[(2 + 4*i + 3)*512 + t] = v.w;
  }
  buf0[t] = 1.0f;
  __syncthreads();
  float lastr = 0.f, lastc = 1.0f;
  #pragma unroll 1
  for (int p = 0; p < 40; ++p){
    const float* rd = (p & 1) ? buf1 : buf0;
    float* wr = (p & 1) ? buf0 : buf1;
    float a0 = 0.f, a1 = 0.f, a2 = 0.f, a3 = 0.f;
    #pragma unroll
    for (int i = 0; i < K3_RC; i += 2){
      float4 w = *(const float4*)&rd[2*i];          // wave-uniform broadcast
      uint32_t m0 = mreg[i], m1 = mreg[i+1];
      a0 += bflo(m0)*w.x; a1 += bfhi(m0)*w.y;
      a2 += bflo(m1)*w.z; a3 += bfhi(m1)*w.w;
    }
    #pragma unroll
    for (int j = 0; j < K3_LC; j += 2){
      float4 w = *(const float4*)&rd[452 + 2*j];    // broadcast
      uint32_t m0 = mlds[j*512 + t];
      uint32_t m1 = mlds[(j + 1)*512 + t];
      a0 += bflo(m0)*w.x; a1 += bfhi(m0)*w.y;
      a2 += bflo(m1)*w.z; a3 += bfhi(m1)*w.w;
    }
    float nv = 1.0f / ((a0 + a1) + (a2 + a3));
    wr[t] = nv;
    if (p & 1) lastc = nv; else lastr = nv;
    __syncthreads();
  }
  int hb = hb0 + hbl;
  r_ws[hb*T_ + t] = lastr;
  c_ws[hb*T_ + t] = lastc;
}

// ---------------------------------------------------------------- K4: out
// out[b,t,h*32+e] = r[t] * sum_s M[t,s] * (c[s]*V[s,e])   (fp32 out)
#define K4_VS 520
__global__ void __launch_bounds__(256)
k4_out(const u16* __restrict__ Mc, const u16* __restrict__ v_ws,
       const float* __restrict__ r_ws, const float* __restrict__ c_ws,
       float* __restrict__ out, int hb0){
  __shared__ u16 vt[32*K4_VS + 8];   // 33296 B
  int th = blockIdx.x;       // t-half
  int hbl = blockIdx.y;
  int hb = hb0 + hbl;
  int h = hb >> 4, b = hb & 15;
  int tid = threadIdx.x;
  const u16* vb = v_ws + (size_t)hb*T_*E_;
  const float* cvec = c_ws + hb*T_;
  #pragma unroll
  for (int rr = 0; rr < 2; ++rr){
    int s = tid + rr*256;
    float cs = cvec[s];
    #pragma unroll
    for (int j4 = 0; j4 < 4; ++j4){
      uint4 v = *(const uint4*)&vb[s*E_ + j4*8];
      uint32_t vv[4] = {v.x,v.y,v.z,v.w};
      #pragma unroll
      for (int j = 0; j < 4; ++j){
        vt[(j4*8 + 2*j    )*K4_VS + s] = f2bf(bflo(vv[j])*cs);
        vt[(j4*8 + 2*j + 1)*K4_VS + s] = f2bf(bfhi(vv[j])*cs);
      }
    }
  }
  __syncthreads();
  int lane = tid & 63, wv = tid >> 6;
  int q_l = lane >> 4, c_l = lane & 15;
  const float* rvec = r_ws + hb*T_;
  const u16* mrow = Mc + (size_t)hbl*T_*T_;
  #pragma unroll 1
  for (int mt = 0; mt < 4; ++mt){
    int t0 = th*256 + (wv*4 + mt)*16;
    floatx4 acc0 = {0,0,0,0}, acc1 = {0,0,0,0};
    #pragma unroll
    for (int kk = 0; kk < 16; ++kk){
      int k0 = kk*32;
      short8 af = *(const short8*)&mrow[(size_t)(t0 + c_l)*T_ + k0 + q_l*8];
      short8 b0 = *(const short8*)&vt[(0  + c_l)*K4_VS + k0 + q_l*8];
      short8 b1 = *(const short8*)&vt[(16 + c_l)*K4_VS + k0 + q_l*8];
      acc0 = __builtin_amdgcn_mfma_f32_16x16x32_bf16(af, b0, acc0, 0, 0, 0);
      acc1 = __builtin_amdgcn_mfma_f32_16x16x32_bf16(af, b1, acc1, 0, 0, 0);
    }
    #pragma unroll
    for (int r = 0; r < 4; ++r){
      int t = t0 + q_l*4 + r;
      float rt = rvec[t];
      out[((size_t)(b*T_ + t))*HE_ + h*E_ + 0  + c_l] = acc0[r]*rt;
      out[((size_t)(b*T_ + t))*HE_ + h*E_ + 16 + c_l] = acc1[r]*rt;
    }
  }
}

// ---------------------------------------------------------------- launch
extern "C" void kernel_launch(void* const* d_in, const int* in_sizes, int n_in,
                              void* d_out, int out_size, void* d_ws, size_t ws_size,
                              hipStream_t stream){
  const float* X  = (const float*)d_in[0];
  const float* te = (const float*)d_in[1];
  const float* Wq = (const float*)d_in[2];
  const float* Wk = (const float*)d_in[3];
  const float* Qb = (const float*)d_in[4];
  const float* Kb = (const float*)d_in[5];
  const float* WV = (const float*)d_in[6];
  const float* Al = (const float*)d_in[7];
  const float* Ll = (const float*)d_in[8];
  float* out = (float*)d_out;
  (void)in_sizes; (void)n_in; (void)out_size;

  // fixed region: 14,188,544 B (< R3's proven 15,237,120)
  char* w = (char*)d_ws;
  float* qw   = (float*)w;  w += 16384;
  float* kw   = (float*)w;  w += 16384;
  u16* lA     = (u16*)w;    w += 524288;
  u16* oml    = (u16*)w;    w += 524288;
  u16* q_ws   = (u16*)w;    w += 4194304;
  u16* k_ws   = (u16*)w;    w += 4194304;
  u16* v_ws   = (u16*)w;    w += 4194304;
  float* r_ws = (float*)w;  w += 262144;
  float* c_ws = (float*)w;  w += 262144;
  // slab (aliased): [Xb 4.19M][QbT 1.05M][KbT 1.05M][Y 33.55M] then reused as Mc
  u16* slab = (u16*)w;
  u16* Xb  = slab;
  u16* QbT = slab + 2097152;
  u16* KbT = slab + 2621440;
  u16* Y   = slab + 3145728;
  u16* Mc  = slab;
  size_t fixed = (size_t)(w - (char*)d_ws);
  size_t slabsz = (ws_size > fixed) ? (ws_size - fixed) : 0;
  int nhb = HB_;
  while (nhb > 1 && (size_t)nhb*T_*T_*2 > slabsz) nhb >>= 1;

  kcvt_x  <<<2048, 256, 0, stream>>>(X, Xb);
  kT_basis<<<dim3(16, 16), 256, 0, stream>>>(Qb, Kb, QbT, KbT);
  k0_meta <<<T_, 64, 0, stream>>>(te, Wq, Wk, qw, kw);
  k_pre   <<<64, 256, 0, stream>>>(Al, Ll, lA, oml);
  k1c_v   <<<T_, 512, 0, stream>>>(Xb, WV, v_ws);
  k1a_gemm<<<dim3(64, 2, 8), 256, 0, stream>>>(Xb, QbT, Y);
  k1b_mix <<<512, 256, 0, stream>>>(Y, qw, q_ws);
  k1a_gemm<<<dim3(64, 2, 8), 256, 0, stream>>>(Xb, KbT, Y);
  k1b_mix <<<512, 256, 0, stream>>>(Y, kw, k_ws);
  for (int hb0 = 0; hb0 < HB_; hb0 += nhb){
    k2a_att    <<<dim3(8, nhb), 256, 0, stream>>>(q_ws, k_ws, lA, oml, Mc, hb0);
    k2b_sym    <<<dim3(36, nhb), 256, 0, stream>>>(Mc);
    k3_sinkhorn<<<nhb, 512, 0, stream>>>(Mc, r_ws, c_ws, hb0);
    k4_out     <<<dim3(2, nhb), 256, 0, stream>>>(Mc, v_ws, r_ws, c_ws, out, hb0);
  }
}

// Round 5
// 2435.960 us; speedup vs baseline: 1.2022x; 1.0554x over previous
//
#include <hip/hip_runtime.h>
#include <hip/hip_bf16.h>
#include <stdint.h>

// FATAttention: B=16, T=512, D=256, H=8, E=32, BASIS=8, 20 sinkhorn iters.
// R5: k3 occupancy pinned via amdgpu_waves_per_eu(2,2) -> 256-VGPR cap so the
// 226-dword row cache stays in registers (R4's __launch_bounds__(512,2) was
// interpreted as 2 blocks/CU -> 128-VGPR cap -> full scratch spill).

#define B_  16
#define T_  512
#define D_  256
#define H_  8
#define E_  32
#define HE_ 256
#define KB_ 8
#define HB_ 128

typedef unsigned short u16;
typedef __attribute__((ext_vector_type(8))) short short8;
typedef __attribute__((ext_vector_type(4))) float floatx4;

__device__ __forceinline__ float bflo(uint32_t u){ return __uint_as_float(u << 16); }
__device__ __forceinline__ float bfhi(uint32_t u){ return __uint_as_float(u & 0xffff0000u); }
__device__ __forceinline__ u16 f2bf(float f){ // RTNE
  uint32_t u = __float_as_uint(f);
  return (u16)((u + 0x7fffu + ((u >> 16) & 1u)) >> 16);
}
__device__ __forceinline__ uint32_t pk2(float a, float b){
  return (uint32_t)f2bf(a) | ((uint32_t)f2bf(b) << 16);
}

// ---------------------------------------------------------------- Kcvt: X->bf16
__global__ void __launch_bounds__(256)
kcvt_x(const float* __restrict__ X, u16* __restrict__ Xb){
  int idx = (blockIdx.x*256 + threadIdx.x)*4;
  float4 v = *(const float4*)(X + idx);
  uint2 o; o.x = pk2(v.x, v.y); o.y = pk2(v.z, v.w);
  *(uint2*)(Xb + idx) = o;
}

// ---------------------------------------------------------------- KT: basis^T
// Q_basis/K_basis [k][d][e] fp32 -> QbT/KbT [k][e][d] bf16
__global__ void __launch_bounds__(256)
kT_basis(const float* __restrict__ Qb, const float* __restrict__ Kb,
         u16* __restrict__ QbT, u16* __restrict__ KbT){
  __shared__ float tile[64][65];
  int slot = blockIdx.y;     // 0..15
  const float* src = (slot < 8) ? Qb + (size_t)slot*D_*HE_ : Kb + (size_t)(slot-8)*D_*HE_;
  u16*         dst = (slot < 8) ? QbT + (size_t)slot*HE_*D_ : KbT + (size_t)(slot-8)*HE_*D_;
  int ti = blockIdx.x >> 2, tj = blockIdx.x & 3;   // d-tile, e-tile
  int tid = threadIdx.x;
  #pragma unroll
  for (int i = 0; i < 16; ++i){
    int idx = tid + 256*i;
    int rr = idx >> 6, cc = idx & 63;
    tile[rr][cc] = src[(size_t)(ti*64 + rr)*HE_ + tj*64 + cc];
  }
  __syncthreads();
  #pragma unroll
  for (int i = 0; i < 16; ++i){
    int idx = tid + 256*i;
    int rr = idx >> 6, cc = idx & 63;
    dst[(size_t)(tj*64 + rr)*D_ + ti*64 + cc] = f2bf(tile[cc][rr]);
  }
}

// ---------------------------------------------------------------- K0: meta
__global__ void k0_meta(const float* __restrict__ te, const float* __restrict__ wq,
                        const float* __restrict__ wk, float* __restrict__ qw,
                        float* __restrict__ kw){
  int t = blockIdx.x;
  int lane = threadIdx.x;        // 64
  int k = lane >> 3, part = lane & 7;
  const float* ta = te + t*D_ + part*32;
  const float* qa = wq + (t*KB_ + k)*D_ + part*32;
  const float* ka = wk + (t*KB_ + k)*D_ + part*32;
  float sq = 0.f, sk = 0.f;
  #pragma unroll
  for (int i = 0; i < 8; ++i){
    float4 a = ((const float4*)ta)[i];
    float4 b = ((const float4*)qa)[i];
    float4 c = ((const float4*)ka)[i];
    sq += a.x*b.x + a.y*b.y + a.z*b.z + a.w*b.w;
    sk += a.x*c.x + a.y*c.y + a.z*c.z + a.w*c.w;
  }
  sq += __shfl_down(sq, 4, 8); sq += __shfl_down(sq, 2, 8); sq += __shfl_down(sq, 1, 8);
  sk += __shfl_down(sk, 4, 8); sk += __shfl_down(sk, 2, 8); sk += __shfl_down(sk, 1, 8);
  if (part == 0){
    qw[t*KB_ + k] = sq * 0.17677669529663687f;  // fold 1/sqrt(32) into q path
    kw[t*KB_ + k] = sk;
  }
}

// -------------------------------------------------------------- Kpre
// lA = sigmoid(L)*0.5*(A+A^T) bf16;  oml = 1-sigmoid(L) bf16
__global__ void __launch_bounds__(256)
k_pre(const float* __restrict__ A, const float* __restrict__ L,
      u16* __restrict__ lA, u16* __restrict__ oml){
  __shared__ float tile[64][65];
  int I = blockIdx.x >> 3, J = blockIdx.x & 7;
  int tid = threadIdx.x;
  #pragma unroll
  for (int i = 0; i < 16; ++i){
    int idx = tid + 256*i;
    int rr = idx >> 6, cc = idx & 63;
    tile[rr][cc] = A[(J*64 + rr)*T_ + I*64 + cc];
  }
  __syncthreads();
  #pragma unroll
  for (int i = 0; i < 16; ++i){
    int idx = tid + 256*i;
    int rr = idx >> 6, cc = idx & 63;
    int t = I*64 + rr, s = J*64 + cc;
    float lamv = 1.0f / (1.0f + __expf(-L[t*T_ + s]));
    float asym = 0.5f*(A[t*T_ + s] + tile[cc][rr]);
    lA[t*T_ + s]  = f2bf(lamv*asym);
    oml[t*T_ + s] = f2bf(1.0f - lamv);
  }
}

// ---------------------------------------------------------------- K1a: Y GEMMs
// Y[kb][bt][e] = Xb[bt][:] . basis[kb][:][e]   (8 GEMMs [8192,256]@[256,256])
__global__ void __launch_bounds__(256)
k1a_gemm(const u16* __restrict__ Xb, const u16* __restrict__ BT, u16* __restrict__ Y){
  __shared__ u16 At[128*40];
  __shared__ u16 Bt[128*40];
  int bt0 = blockIdx.x*128;
  int j   = blockIdx.y;        // e-half
  int kb  = blockIdx.z;
  const u16* Bsrc = BT + (size_t)kb*HE_*D_;
  int tid = threadIdx.x, lane = tid & 63, w = tid >> 6;
  int q_l = lane >> 4, c_l = lane & 15;
  int srow = tid >> 2, sch = (tid & 3)*8;
  floatx4 acc[2][8];
  #pragma unroll
  for (int mt = 0; mt < 2; ++mt)
    #pragma unroll
    for (int n = 0; n < 8; ++n) acc[mt][n] = (floatx4){0,0,0,0};

  #pragma unroll 1
  for (int ks = 0; ks < 8; ++ks){
    int k0 = ks*32;
    if (ks) __syncthreads();
    *(short8*)&At[srow*40 + sch] = *(const short8*)&Xb[(size_t)(bt0 + srow)*D_ + k0 + sch];
    *(short8*)&Bt[srow*40 + sch] = *(const short8*)&Bsrc[(size_t)(j*128 + srow)*D_ + k0 + sch];
    __syncthreads();
    short8 a0 = *(const short8*)&At[(w*32 +  0 + c_l)*40 + q_l*8];
    short8 a1 = *(const short8*)&At[(w*32 + 16 + c_l)*40 + q_l*8];
    #pragma unroll
    for (int n = 0; n < 8; ++n){
      short8 bfr = *(const short8*)&Bt[(n*16 + c_l)*40 + q_l*8];
      acc[0][n] = __builtin_amdgcn_mfma_f32_16x16x32_bf16(a0, bfr, acc[0][n], 0, 0, 0);
      acc[1][n] = __builtin_amdgcn_mfma_f32_16x16x32_bf16(a1, bfr, acc[1][n], 0, 0, 0);
    }
  }
  #pragma unroll
  for (int mt = 0; mt < 2; ++mt)
    #pragma unroll
    for (int n = 0; n < 8; ++n)
      #pragma unroll
      for (int r = 0; r < 4; ++r){
        int row = w*32 + mt*16 + q_l*4 + r;
        int e = j*128 + n*16 + c_l;
        Y[((size_t)kb << 21) + (size_t)(bt0 + row)*HE_ + e] = f2bf(acc[mt][n][r]);
      }
}

// ---------------------------------------------------------------- K1b: mix
// dst[h][b][t][e&31] = sum_k wv[t,k] * Y[k][b*T+t][e]
__global__ void __launch_bounds__(256)
k1b_mix(const u16* __restrict__ Y, const float* __restrict__ wv, u16* __restrict__ dst){
  int tid = threadIdx.x;
  int row = blockIdx.x*16 + (tid >> 4);
  int e0 = (tid & 15)*16;
  int b = row >> 9, t = row & 511;
  float w8[8];
  #pragma unroll
  for (int k = 0; k < 8; ++k) w8[k] = wv[t*8 + k];
  float acc[16];
  #pragma unroll
  for (int i = 0; i < 16; ++i) acc[i] = 0.f;
  #pragma unroll
  for (int k = 0; k < 8; ++k){
    const u16* yp = Y + ((size_t)k << 21) + (size_t)row*HE_ + e0;
    uint4 v0 = *(const uint4*)yp;
    uint4 v1 = *(const uint4*)(yp + 8);
    uint32_t vv[8] = {v0.x,v0.y,v0.z,v0.w,v1.x,v1.y,v1.z,v1.w};
    float wk = w8[k];
    #pragma unroll
    for (int d = 0; d < 8; ++d){
      acc[2*d]   += wk*bflo(vv[d]);
      acc[2*d+1] += wk*bfhi(vv[d]);
    }
  }
  uint4 o0, o1;
  o0.x = pk2(acc[0],acc[1]);   o0.y = pk2(acc[2],acc[3]);
  o0.z = pk2(acc[4],acc[5]);   o0.w = pk2(acc[6],acc[7]);
  o1.x = pk2(acc[8],acc[9]);   o1.y = pk2(acc[10],acc[11]);
  o1.z = pk2(acc[12],acc[13]); o1.w = pk2(acc[14],acc[15]);
  int h = e0 >> 5, off = e0 & 31;
  u16* dp = dst + (((size_t)(h*16 + b)*T_ + t)*E_ + off);
  *(uint4*)dp = o0;
  *(uint4*)(dp + 8) = o1;
}

// ---------------------------------------------------------------- K1c: values
// v_ws[h][b][t][e] = Xb[b,t,:] . W_V[t,:,:]  (per-token GEMM, streams W_V once)
__global__ void __launch_bounds__(512)
k1c_v(const u16* __restrict__ Xb, const float* __restrict__ WV, u16* __restrict__ v_ws){
  __shared__ u16 lds[128*256];   // 65536 B
  int t = blockIdx.x;
  int tid = threadIdx.x;
  int d = tid >> 1, esub = (tid & 1)*64;
  int lane = tid & 63, wv = tid >> 6;
  int q_l = lane >> 4, c_l = lane & 15;
  short8 afrag[8];
  #pragma unroll
  for (int kk = 0; kk < 8; ++kk)
    afrag[kk] = *(const short8*)&Xb[((size_t)c_l*T_ + t)*D_ + kk*32 + q_l*8];
  for (int eh = 0; eh < 2; ++eh){
    #pragma unroll 1
    for (int i = 0; i < 8; ++i){
      int el0 = esub + 8*i;
      int eg0 = eh*128 + el0;
      const float* p = &WV[((size_t)t*D_ + d)*HE_ + eg0];
      float4 m0 = *(const float4*)p;
      float4 m1 = *(const float4*)(p + 4);
      float v[8] = {m0.x,m0.y,m0.z,m0.w,m1.x,m1.y,m1.z,m1.w};
      #pragma unroll
      for (int jj = 0; jj < 8; ++jj){
        int el = el0 + jj;
        lds[el*256 + (((d>>3) ^ (el&31))<<3) + (d&7)] = f2bf(v[jj]);
      }
    }
    __syncthreads();
    floatx4 acc = {0,0,0,0};
    int el = wv*16 + c_l;
    #pragma unroll
    for (int kk = 0; kk < 8; ++kk){
      int c = kk*4 + q_l;
      short8 bfr = *(const short8*)&lds[el*256 + ((c ^ (el&31))<<3)];
      acc = __builtin_amdgcn_mfma_f32_16x16x32_bf16(afrag[kk], bfr, acc, 0, 0, 0);
    }
    int e_full = eh*128 + wv*16 + c_l;
    #pragma unroll
    for (int r = 0; r < 4; ++r){
      int b = q_l*4 + r;
      v_ws[(((size_t)(e_full >> 5)*B_ + b)*T_ + t)*E_ + (e_full & 31)] = f2bf(acc[r]);
    }
    __syncthreads();
  }
}

// ---------------------------------------------------------------- K2a: att
__global__ void __launch_bounds__(256)
k2a_att(const u16* __restrict__ q_ws, const u16* __restrict__ k_ws,
        const u16* __restrict__ lA, const u16* __restrict__ oml,
        u16* __restrict__ Mc, int hb0){
  int tt = blockIdx.x;       // 0..7  (t-tile of 64)
  int hbl = blockIdx.y;
  int hb = hb0 + hbl;
  int tid = threadIdx.x;
  int lane = tid & 63, wv = tid >> 6;
  int q_l = lane >> 4, c_l = lane & 15;
  int t0 = tt*64 + wv*16;
  const u16* qb = q_ws + (size_t)hb*T_*E_;
  const u16* kb = k_ws + (size_t)hb*T_*E_;
  short8 af = *(const short8*)&qb[(t0 + c_l)*E_ + q_l*8];
  floatx4 acc[32];
  #pragma unroll
  for (int st = 0; st < 32; ++st){
    short8 bfr = *(const short8*)&kb[(st*16 + c_l)*E_ + q_l*8];
    floatx4 z = {0,0,0,0};
    acc[st] = __builtin_amdgcn_mfma_f32_16x16x32_bf16(af, bfr, z, 0, 0, 0);
  }
  #pragma unroll
  for (int r = 0; r < 4; ++r){
    float mx = -1e30f;
    #pragma unroll
    for (int st = 0; st < 32; ++st) mx = fmaxf(mx, acc[st][r]);
    mx = fmaxf(mx, __shfl_xor(mx, 1)); mx = fmaxf(mx, __shfl_xor(mx, 2));
    mx = fmaxf(mx, __shfl_xor(mx, 4)); mx = fmaxf(mx, __shfl_xor(mx, 8));
    float sum = 0.f;
    #pragma unroll
    for (int st = 0; st < 32; ++st){ float e = __expf(acc[st][r] - mx); acc[st][r] = e; sum += e; }
    sum += __shfl_xor(sum, 1); sum += __shfl_xor(sum, 2);
    sum += __shfl_xor(sum, 4); sum += __shfl_xor(sum, 8);
    float inv = 1.0f / sum;
    #pragma unroll
    for (int st = 0; st < 32; ++st) acc[st][r] *= inv;
  }
  size_t ob = (size_t)hbl*T_*T_;
  #pragma unroll 1
  for (int st = 0; st < 32; ++st){
    #pragma unroll
    for (int r = 0; r < 4; ++r){
      int t = t0 + q_l*4 + r;
      int s = st*16 + c_l;
      float la = bflo((uint32_t)lA[t*T_ + s]);
      float om = bflo((uint32_t)oml[t*T_ + s]);
      Mc[ob + (size_t)t*T_ + s] = f2bf(la + om*acc[st][r]);
    }
  }
}

// ---------------------------------------------------------------- K2b: M
// In-place: M = exp(0.5*(att + att^T)), triangular 64x64 tile pairs.
__global__ void __launch_bounds__(256)
k2b_sym(u16* __restrict__ Mc){
  __shared__ u16 tA[64][65], tB[64][65];
  int p = blockIdx.x, I = 0;           // p in [0,36): (I,J) with I<=J
  while (p >= 8 - I){ p -= 8 - I; ++I; }
  int J = I + p;
  int hbl = blockIdx.y;
  size_t base = (size_t)hbl*T_*T_;
  int tid = threadIdx.x;
  #pragma unroll
  for (int i = 0; i < 16; ++i){
    int idx = tid + 256*i;
    int rr = idx >> 6, cc = idx & 63;
    tA[rr][cc] = Mc[base + (size_t)(I*64 + rr)*T_ + J*64 + cc];
    tB[rr][cc] = Mc[base + (size_t)(J*64 + rr)*T_ + I*64 + cc];
  }
  __syncthreads();
  #pragma unroll
  for (int i = 0; i < 16; ++i){
    int idx = tid + 256*i;
    int rr = idx >> 6, cc = idx & 63;
    float a = bflo((uint32_t)tA[rr][cc]);
    float b = bflo((uint32_t)tB[cc][rr]);
    Mc[base + (size_t)(I*64 + rr)*T_ + J*64 + cc] = f2bf(__expf(0.5f*(a + b)));
  }
  if (I != J){
    #pragma unroll
    for (int i = 0; i < 16; ++i){
      int idx = tid + 256*i;
      int rr = idx >> 6, cc = idx & 63;
      float a = bflo((uint32_t)tB[rr][cc]);
      float b = bflo((uint32_t)tA[cc][rr]);
      Mc[base + (size_t)(J*64 + rr)*T_ + I*64 + cc] = f2bf(__expf(0.5f*(a + b)));
    }
  }
}

// ---------------------------------------------------------------- K3: sinkhorn
// r = 1/(M c); c = 1/(M r), M symmetric. Row resident: cols 0..451 in 226 VGPR
// dwords, cols 452..511 in 30 LDS dword-columns. 64 KB LDS.
// amdgpu_waves_per_eu(2,2): hard 2 waves/SIMD -> 256-VGPR cap (the launch_bounds
// second-arg route gave a 128 cap and full scratch spill; see R4 counters).
#define K3_RC 226
#define K3_LC 30
__global__ void __launch_bounds__(512)
__attribute__((amdgpu_waves_per_eu(2, 2)))
k3_sinkhorn(const u16* __restrict__ Mc, float* __restrict__ r_ws, float* __restrict__ c_ws,
            int hb0){
  __shared__ uint32_t mlds[K3_LC*512];   // 61440 B
  __shared__ float buf0[512], buf1[512]; // 4096 B  (total exactly 64 KB)
  int hbl = blockIdx.x;
  int t = threadIdx.x;
  const uint4* row = (const uint4*)(Mc + (size_t)(hbl*T_ + t)*T_);
  uint32_t mreg[K3_RC];
  #pragma unroll
  for (int i = 0; i < 56; ++i){          // dwords 0..223
    uint4 v = row[i];
    mreg[4*i] = v.x; mreg[4*i+1] = v.y; mreg[4*i+2] = v.z; mreg[4*i+3] = v.w;
  }
  {                                       // dwords 224..227
    uint4 v = row[56];
    mreg[224] = v.x; mreg[225] = v.y;
    mlds[0*512 + t] = v.z; mlds[1*512 + t] = v.w;
  }
  #pragma unroll
  for (int i = 0; i < 7; ++i){            // dwords 228..255 -> mlds[2..29]
    uint4 v = row[57 + i];
    mlds[(2 + 4*i + 0)*512 + t] = v.x;
    mlds[(2 + 4*i + 1)*512 + t] = v.y;
    mlds[(2 + 4*i + 2)*512 + t] = v.z;
    mlds[(2 + 4*i + 3)*512 + t] = v.w;
  }
  buf0[t] = 1.0f;
  __syncthreads();
  float lastr = 0.f, lastc = 1.0f;
  #pragma unroll 1
  for (int p = 0; p < 40; ++p){
    const float* rd = (p & 1) ? buf1 : buf0;
    float* wr = (p & 1) ? buf0 : buf1;
    float a0 = 0.f, a1 = 0.f, a2 = 0.f, a3 = 0.f;
    #pragma unroll
    for (int i = 0; i < K3_RC; i += 2){
      float4 w = *(const float4*)&rd[2*i];          // wave-uniform broadcast
      uint32_t m0 = mreg[i], m1 = mreg[i+1];
      a0 += bflo(m0)*w.x; a1 += bfhi(m0)*w.y;
      a2 += bflo(m1)*w.z; a3 += bfhi(m1)*w.w;
    }
    #pragma unroll
    for (int j = 0; j < K3_LC; j += 2){
      float4 w = *(const float4*)&rd[452 + 2*j];    // broadcast
      uint32_t m0 = mlds[j*512 + t];
      uint32_t m1 = mlds[(j + 1)*512 + t];
      a0 += bflo(m0)*w.x; a1 += bfhi(m0)*w.y;
      a2 += bflo(m1)*w.z; a3 += bfhi(m1)*w.w;
    }
    float nv = 1.0f / ((a0 + a1) + (a2 + a3));
    wr[t] = nv;
    if (p & 1) lastc = nv; else lastr = nv;
    __syncthreads();
  }
  int hb = hb0 + hbl;
  r_ws[hb*T_ + t] = lastr;
  c_ws[hb*T_ + t] = lastc;
}

// ---------------------------------------------------------------- K4: out
// out[b,t,h*32+e] = r[t] * sum_s M[t,s] * (c[s]*V[s,e])   (fp32 out)
#define K4_VS 520
__global__ void __launch_bounds__(256)
k4_out(const u16* __restrict__ Mc, const u16* __restrict__ v_ws,
       const float* __restrict__ r_ws, const float* __restrict__ c_ws,
       float* __restrict__ out, int hb0){
  __shared__ u16 vt[32*K4_VS + 8];   // 33296 B
  int th = blockIdx.x;       // t-half
  int hbl = blockIdx.y;
  int hb = hb0 + hbl;
  int h = hb >> 4, b = hb & 15;
  int tid = threadIdx.x;
  const u16* vb = v_ws + (size_t)hb*T_*E_;
  const float* cvec = c_ws + hb*T_;
  #pragma unroll
  for (int rr = 0; rr < 2; ++rr){
    int s = tid + rr*256;
    float cs = cvec[s];
    #pragma unroll
    for (int j4 = 0; j4 < 4; ++j4){
      uint4 v = *(const uint4*)&vb[s*E_ + j4*8];
      uint32_t vv[4] = {v.x,v.y,v.z,v.w};
      #pragma unroll
      for (int j = 0; j < 4; ++j){
        vt[(j4*8 + 2*j    )*K4_VS + s] = f2bf(bflo(vv[j])*cs);
        vt[(j4*8 + 2*j + 1)*K4_VS + s] = f2bf(bfhi(vv[j])*cs);
      }
    }
  }
  __syncthreads();
  int lane = tid & 63, wv = tid >> 6;
  int q_l = lane >> 4, c_l = lane & 15;
  const float* rvec = r_ws + hb*T_;
  const u16* mrow = Mc + (size_t)hbl*T_*T_;
  #pragma unroll 1
  for (int mt = 0; mt < 4; ++mt){
    int t0 = th*256 + (wv*4 + mt)*16;
    floatx4 acc0 = {0,0,0,0}, acc1 = {0,0,0,0};
    #pragma unroll
    for (int kk = 0; kk < 16; ++kk){
      int k0 = kk*32;
      short8 af = *(const short8*)&mrow[(size_t)(t0 + c_l)*T_ + k0 + q_l*8];
      short8 b0 = *(const short8*)&vt[(0  + c_l)*K4_VS + k0 + q_l*8];
      short8 b1 = *(const short8*)&vt[(16 + c_l)*K4_VS + k0 + q_l*8];
      acc0 = __builtin_amdgcn_mfma_f32_16x16x32_bf16(af, b0, acc0, 0, 0, 0);
      acc1 = __builtin_amdgcn_mfma_f32_16x16x32_bf16(af, b1, acc1, 0, 0, 0);
    }
    #pragma unroll
    for (int r = 0; r < 4; ++r){
      int t = t0 + q_l*4 + r;
      float rt = rvec[t];
      out[((size_t)(b*T_ + t))*HE_ + h*E_ + 0  + c_l] = acc0[r]*rt;
      out[((size_t)(b*T_ + t))*HE_ + h*E_ + 16 + c_l] = acc1[r]*rt;
    }
  }
}

// ---------------------------------------------------------------- launch
extern "C" void kernel_launch(void* const* d_in, const int* in_sizes, int n_in,
                              void* d_out, int out_size, void* d_ws, size_t ws_size,
                              hipStream_t stream){
  const float* X  = (const float*)d_in[0];
  const float* te = (const float*)d_in[1];
  const float* Wq = (const float*)d_in[2];
  const float* Wk = (const float*)d_in[3];
  const float* Qb = (const float*)d_in[4];
  const float* Kb = (const float*)d_in[5];
  const float* WV = (const float*)d_in[6];
  const float* Al = (const float*)d_in[7];
  const float* Ll = (const float*)d_in[8];
  float* out = (float*)d_out;
  (void)in_sizes; (void)n_in; (void)out_size;

  char* w = (char*)d_ws;
  float* qw   = (float*)w;  w += 16384;
  float* kw   = (float*)w;  w += 16384;
  u16* lA     = (u16*)w;    w += 524288;
  u16* oml    = (u16*)w;    w += 524288;
  u16* q_ws   = (u16*)w;    w += 4194304;
  u16* k_ws   = (u16*)w;    w += 4194304;
  u16* v_ws   = (u16*)w;    w += 4194304;
  float* r_ws = (float*)w;  w += 262144;
  float* c_ws = (float*)w;  w += 262144;
  // slab (aliased): [Xb 4.19M][QbT 1.05M][KbT 1.05M][Y 33.55M] then reused as Mc
  u16* slab = (u16*)w;
  u16* Xb  = slab;
  u16* QbT = slab + 2097152;
  u16* KbT = slab + 2621440;
  u16* Y   = slab + 3145728;
  u16* Mc  = slab;
  size_t fixed = (size_t)(w - (char*)d_ws);
  size_t slabsz = (ws_size > fixed) ? (ws_size - fixed) : 0;
  int nhb = HB_;
  while (nhb > 1 && (size_t)nhb*T_*T_*2 > slabsz) nhb >>= 1;

  kcvt_x  <<<2048, 256, 0, stream>>>(X, Xb);
  kT_basis<<<dim3(16, 16), 256, 0, stream>>>(Qb, Kb, QbT, KbT);
  k0_meta <<<T_, 64, 0, stream>>>(te, Wq, Wk, qw, kw);
  k_pre   <<<64, 256, 0, stream>>>(Al, Ll, lA, oml);
  k1c_v   <<<T_, 512, 0, stream>>>(Xb, WV, v_ws);
  k1a_gemm<<<dim3(64, 2, 8), 256, 0, stream>>>(Xb, QbT, Y);
  k1b_mix <<<512, 256, 0, stream>>>(Y, qw, q_ws);
  k1a_gemm<<<dim3(64, 2, 8), 256, 0, stream>>>(Xb, KbT, Y);
  k1b_mix <<<512, 256, 0, stream>>>(Y, kw, k_ws);
  for (int hb0 = 0; hb0 < HB_; hb0 += nhb){
    k2a_att    <<<dim3(8, nhb), 256, 0, stream>>>(q_ws, k_ws, lA, oml, Mc, hb0);
    k2b_sym    <<<dim3(36, nhb), 256, 0, stream>>>(Mc);
    k3_sinkhorn<<<nhb, 512, 0, stream>>>(Mc, r_ws, c_ws, hb0);
    k4_out     <<<dim3(2, nhb), 256, 0, stream>>>(Mc, v_ws, r_ws, c_ws, out, hb0);
  }
}

// Round 6
// 1577.283 us; speedup vs baseline: 1.8567x; 1.5444x over previous
//
#include <hip/hip_runtime.h>
#include <hip/hip_bf16.h>
#include <stdint.h>

// FATAttention: B=16, T=512, D=256, H=8, E=32, BASIS=8, 20 sinkhorn iters.
// R6: k3 rebuilt for register residency: 256 thr/block, 2 rows/thread
// (180 reg-dwords + 76 LDS-dwordcols per row), 156 KB dynamic LDS so only
// one block fits per CU -> compiler targets 1 wave/SIMD -> 512-reg unified
// budget (R4/R5: 64KB LDS implied 2 blocks/CU -> 128-reg budget -> full spill).

#define B_  16
#define T_  512
#define D_  256
#define H_  8
#define E_  32
#define HE_ 256
#define KB_ 8
#define HB_ 128

typedef unsigned short u16;
typedef __attribute__((ext_vector_type(8))) short short8;
typedef __attribute__((ext_vector_type(4))) float floatx4;

__device__ __forceinline__ float bflo(uint32_t u){ return __uint_as_float(u << 16); }
__device__ __forceinline__ float bfhi(uint32_t u){ return __uint_as_float(u & 0xffff0000u); }
__device__ __forceinline__ u16 f2bf(float f){ // RTNE
  uint32_t u = __float_as_uint(f);
  return (u16)((u + 0x7fffu + ((u >> 16) & 1u)) >> 16);
}
__device__ __forceinline__ uint32_t pk2(float a, float b){
  return (uint32_t)f2bf(a) | ((uint32_t)f2bf(b) << 16);
}

// ---------------------------------------------------------------- Kcvt: X->bf16
__global__ void __launch_bounds__(256)
kcvt_x(const float* __restrict__ X, u16* __restrict__ Xb){
  int idx = (blockIdx.x*256 + threadIdx.x)*4;
  float4 v = *(const float4*)(X + idx);
  uint2 o; o.x = pk2(v.x, v.y); o.y = pk2(v.z, v.w);
  *(uint2*)(Xb + idx) = o;
}

// ---------------------------------------------------------------- KT: basis^T
// Q_basis/K_basis [k][d][e] fp32 -> QbT/KbT [k][e][d] bf16
__global__ void __launch_bounds__(256)
kT_basis(const float* __restrict__ Qb, const float* __restrict__ Kb,
         u16* __restrict__ QbT, u16* __restrict__ KbT){
  __shared__ float tile[64][65];
  int slot = blockIdx.y;     // 0..15
  const float* src = (slot < 8) ? Qb + (size_t)slot*D_*HE_ : Kb + (size_t)(slot-8)*D_*HE_;
  u16*         dst = (slot < 8) ? QbT + (size_t)slot*HE_*D_ : KbT + (size_t)(slot-8)*HE_*D_;
  int ti = blockIdx.x >> 2, tj = blockIdx.x & 3;   // d-tile, e-tile
  int tid = threadIdx.x;
  #pragma unroll
  for (int i = 0; i < 16; ++i){
    int idx = tid + 256*i;
    int rr = idx >> 6, cc = idx & 63;
    tile[rr][cc] = src[(size_t)(ti*64 + rr)*HE_ + tj*64 + cc];
  }
  __syncthreads();
  #pragma unroll
  for (int i = 0; i < 16; ++i){
    int idx = tid + 256*i;
    int rr = idx >> 6, cc = idx & 63;
    dst[(size_t)(tj*64 + rr)*D_ + ti*64 + cc] = f2bf(tile[cc][rr]);
  }
}

// ---------------------------------------------------------------- K0: meta
__global__ void k0_meta(const float* __restrict__ te, const float* __restrict__ wq,
                        const float* __restrict__ wk, float* __restrict__ qw,
                        float* __restrict__ kw){
  int t = blockIdx.x;
  int lane = threadIdx.x;        // 64
  int k = lane >> 3, part = lane & 7;
  const float* ta = te + t*D_ + part*32;
  const float* qa = wq + (t*KB_ + k)*D_ + part*32;
  const float* ka = wk + (t*KB_ + k)*D_ + part*32;
  float sq = 0.f, sk = 0.f;
  #pragma unroll
  for (int i = 0; i < 8; ++i){
    float4 a = ((const float4*)ta)[i];
    float4 b = ((const float4*)qa)[i];
    float4 c = ((const float4*)ka)[i];
    sq += a.x*b.x + a.y*b.y + a.z*b.z + a.w*b.w;
    sk += a.x*c.x + a.y*c.y + a.z*c.z + a.w*c.w;
  }
  sq += __shfl_down(sq, 4, 8); sq += __shfl_down(sq, 2, 8); sq += __shfl_down(sq, 1, 8);
  sk += __shfl_down(sk, 4, 8); sk += __shfl_down(sk, 2, 8); sk += __shfl_down(sk, 1, 8);
  if (part == 0){
    qw[t*KB_ + k] = sq * 0.17677669529663687f;  // fold 1/sqrt(32) into q path
    kw[t*KB_ + k] = sk;
  }
}

// -------------------------------------------------------------- Kpre
// lA = sigmoid(L)*0.5*(A+A^T) bf16;  oml = 1-sigmoid(L) bf16
__global__ void __launch_bounds__(256)
k_pre(const float* __restrict__ A, const float* __restrict__ L,
      u16* __restrict__ lA, u16* __restrict__ oml){
  __shared__ float tile[64][65];
  int I = blockIdx.x >> 3, J = blockIdx.x & 7;
  int tid = threadIdx.x;
  #pragma unroll
  for (int i = 0; i < 16; ++i){
    int idx = tid + 256*i;
    int rr = idx >> 6, cc = idx & 63;
    tile[rr][cc] = A[(J*64 + rr)*T_ + I*64 + cc];
  }
  __syncthreads();
  #pragma unroll
  for (int i = 0; i < 16; ++i){
    int idx = tid + 256*i;
    int rr = idx >> 6, cc = idx & 63;
    int t = I*64 + rr, s = J*64 + cc;
    float lamv = 1.0f / (1.0f + __expf(-L[t*T_ + s]));
    float asym = 0.5f*(A[t*T_ + s] + tile[cc][rr]);
    lA[t*T_ + s]  = f2bf(lamv*asym);
    oml[t*T_ + s] = f2bf(1.0f - lamv);
  }
}

// ---------------------------------------------------------------- K1a: Y GEMMs
// Y[kb][bt][e] = Xb[bt][:] . basis[kb][:][e]   (8 GEMMs [8192,256]@[256,256])
__global__ void __launch_bounds__(256)
k1a_gemm(const u16* __restrict__ Xb, const u16* __restrict__ BT, u16* __restrict__ Y){
  __shared__ u16 At[128*40];
  __shared__ u16 Bt[128*40];
  int bt0 = blockIdx.x*128;
  int j   = blockIdx.y;        // e-half
  int kb  = blockIdx.z;
  const u16* Bsrc = BT + (size_t)kb*HE_*D_;
  int tid = threadIdx.x, lane = tid & 63, w = tid >> 6;
  int q_l = lane >> 4, c_l = lane & 15;
  int srow = tid >> 2, sch = (tid & 3)*8;
  floatx4 acc[2][8];
  #pragma unroll
  for (int mt = 0; mt < 2; ++mt)
    #pragma unroll
    for (int n = 0; n < 8; ++n) acc[mt][n] = (floatx4){0,0,0,0};

  #pragma unroll 1
  for (int ks = 0; ks < 8; ++ks){
    int k0 = ks*32;
    if (ks) __syncthreads();
    *(short8*)&At[srow*40 + sch] = *(const short8*)&Xb[(size_t)(bt0 + srow)*D_ + k0 + sch];
    *(short8*)&Bt[srow*40 + sch] = *(const short8*)&Bsrc[(size_t)(j*128 + srow)*D_ + k0 + sch];
    __syncthreads();
    short8 a0 = *(const short8*)&At[(w*32 +  0 + c_l)*40 + q_l*8];
    short8 a1 = *(const short8*)&At[(w*32 + 16 + c_l)*40 + q_l*8];
    #pragma unroll
    for (int n = 0; n < 8; ++n){
      short8 bfr = *(const short8*)&Bt[(n*16 + c_l)*40 + q_l*8];
      acc[0][n] = __builtin_amdgcn_mfma_f32_16x16x32_bf16(a0, bfr, acc[0][n], 0, 0, 0);
      acc[1][n] = __builtin_amdgcn_mfma_f32_16x16x32_bf16(a1, bfr, acc[1][n], 0, 0, 0);
    }
  }
  #pragma unroll
  for (int mt = 0; mt < 2; ++mt)
    #pragma unroll
    for (int n = 0; n < 8; ++n)
      #pragma unroll
      for (int r = 0; r < 4; ++r){
        int row = w*32 + mt*16 + q_l*4 + r;
        int e = j*128 + n*16 + c_l;
        Y[((size_t)kb << 21) + (size_t)(bt0 + row)*HE_ + e] = f2bf(acc[mt][n][r]);
      }
}

// ---------------------------------------------------------------- K1b: mix
// dst[h][b][t][e&31] = sum_k wv[t,k] * Y[k][b*T+t][e]
__global__ void __launch_bounds__(256)
k1b_mix(const u16* __restrict__ Y, const float* __restrict__ wv, u16* __restrict__ dst){
  int tid = threadIdx.x;
  int row = blockIdx.x*16 + (tid >> 4);
  int e0 = (tid & 15)*16;
  int b = row >> 9, t = row & 511;
  float w8[8];
  #pragma unroll
  for (int k = 0; k < 8; ++k) w8[k] = wv[t*8 + k];
  float acc[16];
  #pragma unroll
  for (int i = 0; i < 16; ++i) acc[i] = 0.f;
  #pragma unroll
  for (int k = 0; k < 8; ++k){
    const u16* yp = Y + ((size_t)k << 21) + (size_t)row*HE_ + e0;
    uint4 v0 = *(const uint4*)yp;
    uint4 v1 = *(const uint4*)(yp + 8);
    uint32_t vv[8] = {v0.x,v0.y,v0.z,v0.w,v1.x,v1.y,v1.z,v1.w};
    float wk = w8[k];
    #pragma unroll
    for (int d = 0; d < 8; ++d){
      acc[2*d]   += wk*bflo(vv[d]);
      acc[2*d+1] += wk*bfhi(vv[d]);
    }
  }
  uint4 o0, o1;
  o0.x = pk2(acc[0],acc[1]);   o0.y = pk2(acc[2],acc[3]);
  o0.z = pk2(acc[4],acc[5]);   o0.w = pk2(acc[6],acc[7]);
  o1.x = pk2(acc[8],acc[9]);   o1.y = pk2(acc[10],acc[11]);
  o1.z = pk2(acc[12],acc[13]); o1.w = pk2(acc[14],acc[15]);
  int h = e0 >> 5, off = e0 & 31;
  u16* dp = dst + (((size_t)(h*16 + b)*T_ + t)*E_ + off);
  *(uint4*)dp = o0;
  *(uint4*)(dp + 8) = o1;
}

// ---------------------------------------------------------------- K1c: values
// v_ws[h][b][t][e] = Xb[b,t,:] . W_V[t,:,:]  (per-token GEMM, streams W_V once)
__global__ void __launch_bounds__(512)
k1c_v(const u16* __restrict__ Xb, const float* __restrict__ WV, u16* __restrict__ v_ws){
  __shared__ u16 lds[128*256];   // 65536 B
  int t = blockIdx.x;
  int tid = threadIdx.x;
  int d = tid >> 1, esub = (tid & 1)*64;
  int lane = tid & 63, wv = tid >> 6;
  int q_l = lane >> 4, c_l = lane & 15;
  short8 afrag[8];
  #pragma unroll
  for (int kk = 0; kk < 8; ++kk)
    afrag[kk] = *(const short8*)&Xb[((size_t)c_l*T_ + t)*D_ + kk*32 + q_l*8];
  for (int eh = 0; eh < 2; ++eh){
    #pragma unroll 1
    for (int i = 0; i < 8; ++i){
      int el0 = esub + 8*i;
      int eg0 = eh*128 + el0;
      const float* p = &WV[((size_t)t*D_ + d)*HE_ + eg0];
      float4 m0 = *(const float4*)p;
      float4 m1 = *(const float4*)(p + 4);
      float v[8] = {m0.x,m0.y,m0.z,m0.w,m1.x,m1.y,m1.z,m1.w};
      #pragma unroll
      for (int jj = 0; jj < 8; ++jj){
        int el = el0 + jj;
        lds[el*256 + (((d>>3) ^ (el&31))<<3) + (d&7)] = f2bf(v[jj]);
      }
    }
    __syncthreads();
    floatx4 acc = {0,0,0,0};
    int el = wv*16 + c_l;
    #pragma unroll
    for (int kk = 0; kk < 8; ++kk){
      int c = kk*4 + q_l;
      short8 bfr = *(const short8*)&lds[el*256 + ((c ^ (el&31))<<3)];
      acc = __builtin_amdgcn_mfma_f32_16x16x32_bf16(afrag[kk], bfr, acc, 0, 0, 0);
    }
    int e_full = eh*128 + wv*16 + c_l;
    #pragma unroll
    for (int r = 0; r < 4; ++r){
      int b = q_l*4 + r;
      v_ws[(((size_t)(e_full >> 5)*B_ + b)*T_ + t)*E_ + (e_full & 31)] = f2bf(acc[r]);
    }
    __syncthreads();
  }
}

// ---------------------------------------------------------------- K2a: att
__global__ void __launch_bounds__(256)
k2a_att(const u16* __restrict__ q_ws, const u16* __restrict__ k_ws,
        const u16* __restrict__ lA, const u16* __restrict__ oml,
        u16* __restrict__ Mc, int hb0){
  int tt = blockIdx.x;       // 0..7  (t-tile of 64)
  int hbl = blockIdx.y;
  int hb = hb0 + hbl;
  int tid = threadIdx.x;
  int lane = tid & 63, wv = tid >> 6;
  int q_l = lane >> 4, c_l = lane & 15;
  int t0 = tt*64 + wv*16;
  const u16* qb = q_ws + (size_t)hb*T_*E_;
  const u16* kb = k_ws + (size_t)hb*T_*E_;
  short8 af = *(const short8*)&qb[(t0 + c_l)*E_ + q_l*8];
  floatx4 acc[32];
  #pragma unroll
  for (int st = 0; st < 32; ++st){
    short8 bfr = *(const short8*)&kb[(st*16 + c_l)*E_ + q_l*8];
    floatx4 z = {0,0,0,0};
    acc[st] = __builtin_amdgcn_mfma_f32_16x16x32_bf16(af, bfr, z, 0, 0, 0);
  }
  #pragma unroll
  for (int r = 0; r < 4; ++r){
    float mx = -1e30f;
    #pragma unroll
    for (int st = 0; st < 32; ++st) mx = fmaxf(mx, acc[st][r]);
    mx = fmaxf(mx, __shfl_xor(mx, 1)); mx = fmaxf(mx, __shfl_xor(mx, 2));
    mx = fmaxf(mx, __shfl_xor(mx, 4)); mx = fmaxf(mx, __shfl_xor(mx, 8));
    float sum = 0.f;
    #pragma unroll
    for (int st = 0; st < 32; ++st){ float e = __expf(acc[st][r] - mx); acc[st][r] = e; sum += e; }
    sum += __shfl_xor(sum, 1); sum += __shfl_xor(sum, 2);
    sum += __shfl_xor(sum, 4); sum += __shfl_xor(sum, 8);
    float inv = 1.0f / sum;
    #pragma unroll
    for (int st = 0; st < 32; ++st) acc[st][r] *= inv;
  }
  size_t ob = (size_t)hbl*T_*T_;
  #pragma unroll 1
  for (int st = 0; st < 32; ++st){
    #pragma unroll
    for (int r = 0; r < 4; ++r){
      int t = t0 + q_l*4 + r;
      int s = st*16 + c_l;
      float la = bflo((uint32_t)lA[t*T_ + s]);
      float om = bflo((uint32_t)oml[t*T_ + s]);
      Mc[ob + (size_t)t*T_ + s] = f2bf(la + om*acc[st][r]);
    }
  }
}

// ---------------------------------------------------------------- K2b: M
// In-place: M = exp(0.5*(att + att^T)), triangular 64x64 tile pairs.
__global__ void __launch_bounds__(256)
k2b_sym(u16* __restrict__ Mc){
  __shared__ u16 tA[64][65], tB[64][65];
  int p = blockIdx.x, I = 0;           // p in [0,36): (I,J) with I<=J
  while (p >= 8 - I){ p -= 8 - I; ++I; }
  int J = I + p;
  int hbl = blockIdx.y;
  size_t base = (size_t)hbl*T_*T_;
  int tid = threadIdx.x;
  #pragma unroll
  for (int i = 0; i < 16; ++i){
    int idx = tid + 256*i;
    int rr = idx >> 6, cc = idx & 63;
    tA[rr][cc] = Mc[base + (size_t)(I*64 + rr)*T_ + J*64 + cc];
    tB[rr][cc] = Mc[base + (size_t)(J*64 + rr)*T_ + I*64 + cc];
  }
  __syncthreads();
  #pragma unroll
  for (int i = 0; i < 16; ++i){
    int idx = tid + 256*i;
    int rr = idx >> 6, cc = idx & 63;
    float a = bflo((uint32_t)tA[rr][cc]);
    float b = bflo((uint32_t)tB[cc][rr]);
    Mc[base + (size_t)(I*64 + rr)*T_ + J*64 + cc] = f2bf(__expf(0.5f*(a + b)));
  }
  if (I != J){
    #pragma unroll
    for (int i = 0; i < 16; ++i){
      int idx = tid + 256*i;
      int rr = idx >> 6, cc = idx & 63;
      float a = bflo((uint32_t)tB[rr][cc]);
      float b = bflo((uint32_t)tA[cc][rr]);
      Mc[base + (size_t)(J*64 + rr)*T_ + I*64 + cc] = f2bf(__expf(0.5f*(a + b)));
    }
  }
}

// ---------------------------------------------------------------- K3: sinkhorn
// r = 1/(M c); c = 1/(M r), M symmetric. 256 threads, 2 rows/thread.
// Per row: cols 0..359 in 180 reg-dwords, cols 360..511 in 76 LDS dword-cols.
// Dynamic LDS 156 KB -> 1 block/CU -> compiler targets 1 wave/SIMD -> 512-reg
// unified budget; demand ~390 regs (no spill; m08: clean through ~450).
#define K3_RD 180
#define K3_LD 76
#define K3_LDS (K3_LD*512*4 + 2*512*4)   // 159744 B
__global__ void __launch_bounds__(256)
k3_sinkhorn(const u16* __restrict__ Mc, float* __restrict__ r_ws, float* __restrict__ c_ws,
            int hb0){
  extern __shared__ char dynsmem[];
  uint32_t* mlds = (uint32_t*)dynsmem;                 // [76][512]
  float* buf0 = (float*)(dynsmem + K3_LD*512*4);
  float* buf1 = buf0 + 512;
  int hbl = blockIdx.x;
  int t = threadIdx.x;                                 // 0..255
  const uint4* row0 = (const uint4*)(Mc + ((size_t)hbl*T_ + t)*T_);
  const uint4* row1 = (const uint4*)(Mc + ((size_t)hbl*T_ + t + 256)*T_);
  uint32_t m0[K3_RD], m1[K3_RD];
  #pragma unroll
  for (int i = 0; i < 45; ++i){
    uint4 v = row0[i];
    m0[4*i] = v.x; m0[4*i+1] = v.y; m0[4*i+2] = v.z; m0[4*i+3] = v.w;
  }
  #pragma unroll
  for (int i = 0; i < 45; ++i){
    uint4 v = row1[i];
    m1[4*i] = v.x; m1[4*i+1] = v.y; m1[4*i+2] = v.z; m1[4*i+3] = v.w;
  }
  #pragma unroll
  for (int i = 0; i < 19; ++i){                        // dwords 180..255
    uint4 v = row0[45 + i];
    mlds[(4*i + 0)*512 + t] = v.x;
    mlds[(4*i + 1)*512 + t] = v.y;
    mlds[(4*i + 2)*512 + t] = v.z;
    mlds[(4*i + 3)*512 + t] = v.w;
  }
  #pragma unroll
  for (int i = 0; i < 19; ++i){
    uint4 v = row1[45 + i];
    mlds[(4*i + 0)*512 + t + 256] = v.x;
    mlds[(4*i + 1)*512 + t + 256] = v.y;
    mlds[(4*i + 2)*512 + t + 256] = v.z;
    mlds[(4*i + 3)*512 + t + 256] = v.w;
  }
  buf0[t] = 1.0f; buf0[t + 256] = 1.0f;
  __syncthreads();
  float lr0 = 0.f, lr1 = 0.f, lc0 = 1.0f, lc1 = 1.0f;
  #pragma unroll 1
  for (int p = 0; p < 40; ++p){
    const float* rd = (p & 1) ? buf1 : buf0;
    float* wr = (p & 1) ? buf0 : buf1;
    float a00=0.f,a01=0.f,a02=0.f,a03=0.f, a10=0.f,a11=0.f,a12=0.f,a13=0.f;
    #pragma unroll
    for (int i = 0; i < K3_RD; i += 2){
      float4 w = *(const float4*)&rd[2*i];             // wave-uniform broadcast
      uint32_t x0 = m0[i], x1 = m0[i+1], y0 = m1[i], y1 = m1[i+1];
      a00 += bflo(x0)*w.x; a01 += bfhi(x0)*w.y; a02 += bflo(x1)*w.z; a03 += bfhi(x1)*w.w;
      a10 += bflo(y0)*w.x; a11 += bfhi(y0)*w.y; a12 += bflo(y1)*w.z; a13 += bfhi(y1)*w.w;
    }
    #pragma unroll
    for (int j = 0; j < K3_LD; j += 2){
      float4 w = *(const float4*)&rd[360 + 2*j];       // broadcast
      uint32_t x0 = mlds[j*512 + t],       x1 = mlds[(j+1)*512 + t];
      uint32_t y0 = mlds[j*512 + t + 256], y1 = mlds[(j+1)*512 + t + 256];
      a00 += bflo(x0)*w.x; a01 += bfhi(x0)*w.y; a02 += bflo(x1)*w.z; a03 += bfhi(x1)*w.w;
      a10 += bflo(y0)*w.x; a11 += bfhi(y0)*w.y; a12 += bflo(y1)*w.z; a13 += bfhi(y1)*w.w;
    }
    float nv0 = 1.0f / ((a00 + a01) + (a02 + a03));
    float nv1 = 1.0f / ((a10 + a11) + (a12 + a13));
    wr[t] = nv0; wr[t + 256] = nv1;
    if (p & 1){ lc0 = nv0; lc1 = nv1; } else { lr0 = nv0; lr1 = nv1; }
    __syncthreads();
  }
  int hb = hb0 + hbl;
  r_ws[hb*T_ + t] = lr0; r_ws[hb*T_ + t + 256] = lr1;
  c_ws[hb*T_ + t] = lc0; c_ws[hb*T_ + t + 256] = lc1;
}

// ---------------------------------------------------------------- K4: out
// out[b,t,h*32+e] = r[t] * sum_s M[t,s] * (c[s]*V[s,e])   (fp32 out)
#define K4_VS 520
__global__ void __launch_bounds__(256)
k4_out(const u16* __restrict__ Mc, const u16* __restrict__ v_ws,
       const float* __restrict__ r_ws, const float* __restrict__ c_ws,
       float* __restrict__ out, int hb0){
  __shared__ u16 vt[32*K4_VS + 8];   // 33296 B
  int th = blockIdx.x;       // t-half
  int hbl = blockIdx.y;
  int hb = hb0 + hbl;
  int h = hb >> 4, b = hb & 15;
  int tid = threadIdx.x;
  const u16* vb = v_ws + (size_t)hb*T_*E_;
  const float* cvec = c_ws + hb*T_;
  #pragma unroll
  for (int rr = 0; rr < 2; ++rr){
    int s = tid + rr*256;
    float cs = cvec[s];
    #pragma unroll
    for (int j4 = 0; j4 < 4; ++j4){
      uint4 v = *(const uint4*)&vb[s*E_ + j4*8];
      uint32_t vv[4] = {v.x,v.y,v.z,v.w};
      #pragma unroll
      for (int j = 0; j < 4; ++j){
        vt[(j4*8 + 2*j    )*K4_VS + s] = f2bf(bflo(vv[j])*cs);
        vt[(j4*8 + 2*j + 1)*K4_VS + s] = f2bf(bfhi(vv[j])*cs);
      }
    }
  }
  __syncthreads();
  int lane = tid & 63, wv = tid >> 6;
  int q_l = lane >> 4, c_l = lane & 15;
  const float* rvec = r_ws + hb*T_;
  const u16* mrow = Mc + (size_t)hbl*T_*T_;
  #pragma unroll 1
  for (int mt = 0; mt < 4; ++mt){
    int t0 = th*256 + (wv*4 + mt)*16;
    floatx4 acc0 = {0,0,0,0}, acc1 = {0,0,0,0};
    #pragma unroll
    for (int kk = 0; kk < 16; ++kk){
      int k0 = kk*32;
      short8 af = *(const short8*)&mrow[(size_t)(t0 + c_l)*T_ + k0 + q_l*8];
      short8 b0 = *(const short8*)&vt[(0  + c_l)*K4_VS + k0 + q_l*8];
      short8 b1 = *(const short8*)&vt[(16 + c_l)*K4_VS + k0 + q_l*8];
      acc0 = __builtin_amdgcn_mfma_f32_16x16x32_bf16(af, b0, acc0, 0, 0, 0);
      acc1 = __builtin_amdgcn_mfma_f32_16x16x32_bf16(af, b1, acc1, 0, 0, 0);
    }
    #pragma unroll
    for (int r = 0; r < 4; ++r){
      int t = t0 + q_l*4 + r;
      float rt = rvec[t];
      out[((size_t)(b*T_ + t))*HE_ + h*E_ + 0  + c_l] = acc0[r]*rt;
      out[((size_t)(b*T_ + t))*HE_ + h*E_ + 16 + c_l] = acc1[r]*rt;
    }
  }
}

// ---------------------------------------------------------------- launch
extern "C" void kernel_launch(void* const* d_in, const int* in_sizes, int n_in,
                              void* d_out, int out_size, void* d_ws, size_t ws_size,
                              hipStream_t stream){
  const float* X  = (const float*)d_in[0];
  const float* te = (const float*)d_in[1];
  const float* Wq = (const float*)d_in[2];
  const float* Wk = (const float*)d_in[3];
  const float* Qb = (const float*)d_in[4];
  const float* Kb = (const float*)d_in[5];
  const float* WV = (const float*)d_in[6];
  const float* Al = (const float*)d_in[7];
  const float* Ll = (const float*)d_in[8];
  float* out = (float*)d_out;
  (void)in_sizes; (void)n_in; (void)out_size;

  char* w = (char*)d_ws;
  float* qw   = (float*)w;  w += 16384;
  float* kw   = (float*)w;  w += 16384;
  u16* lA     = (u16*)w;    w += 524288;
  u16* oml    = (u16*)w;    w += 524288;
  u16* q_ws   = (u16*)w;    w += 4194304;
  u16* k_ws   = (u16*)w;    w += 4194304;
  u16* v_ws   = (u16*)w;    w += 4194304;
  float* r_ws = (float*)w;  w += 262144;
  float* c_ws = (float*)w;  w += 262144;
  // slab (aliased): [Xb 4.19M][QbT 1.05M][KbT 1.05M][Y 33.55M] then reused as Mc
  u16* slab = (u16*)w;
  u16* Xb  = slab;
  u16* QbT = slab + 2097152;
  u16* KbT = slab + 2621440;
  u16* Y   = slab + 3145728;
  u16* Mc  = slab;
  size_t fixed = (size_t)(w - (char*)d_ws);
  size_t slabsz = (ws_size > fixed) ? (ws_size - fixed) : 0;
  int nhb = HB_;
  while (nhb > 1 && (size_t)nhb*T_*T_*2 > slabsz) nhb >>= 1;

  // >64KB dynamic-LDS opt-in for k3 (host-side, idempotent, capture-safe)
  hipFuncSetAttribute((const void*)k3_sinkhorn,
                      hipFuncAttributeMaxDynamicSharedMemorySize, K3_LDS);

  kcvt_x  <<<2048, 256, 0, stream>>>(X, Xb);
  kT_basis<<<dim3(16, 16), 256, 0, stream>>>(Qb, Kb, QbT, KbT);
  k0_meta <<<T_, 64, 0, stream>>>(te, Wq, Wk, qw, kw);
  k_pre   <<<64, 256, 0, stream>>>(Al, Ll, lA, oml);
  k1c_v   <<<T_, 512, 0, stream>>>(Xb, WV, v_ws);
  k1a_gemm<<<dim3(64, 2, 8), 256, 0, stream>>>(Xb, QbT, Y);
  k1b_mix <<<512, 256, 0, stream>>>(Y, qw, q_ws);
  k1a_gemm<<<dim3(64, 2, 8), 256, 0, stream>>>(Xb, KbT, Y);
  k1b_mix <<<512, 256, 0, stream>>>(Y, kw, k_ws);
  for (int hb0 = 0; hb0 < HB_; hb0 += nhb){
    k2a_att    <<<dim3(8, nhb), 256, 0, stream>>>(q_ws, k_ws, lA, oml, Mc, hb0);
    k2b_sym    <<<dim3(36, nhb), 256, 0, stream>>>(Mc);
    k3_sinkhorn<<<nhb, 256, K3_LDS, stream>>>(Mc, r_ws, c_ws, hb0);
    k4_out     <<<dim3(2, nhb), 256, 0, stream>>>(Mc, v_ws, r_ws, c_ws, out, hb0);
  }
}